// Round 15
// baseline (468.821 us; speedup 1.0000x reference)
//
#include <hip/hip_runtime.h>
#include <hip/hip_bf16.h>
#include <math.h>

// N=50000, E=400000, F_IN=128, HID=64, OUT=40, H=4
#define SLOPE 0.2f

typedef unsigned short bf16_t;
typedef short bh8 __attribute__((ext_vector_type(8)));
typedef unsigned short us8 __attribute__((ext_vector_type(8)));
typedef float f32x4 __attribute__((ext_vector_type(4)));

__device__ __forceinline__ float bf2f(bf16_t x) {
    return __uint_as_float((unsigned)x << 16);
}
__device__ __forceinline__ bf16_t f2bf(float v) {
    unsigned u = __float_as_uint(v);
    return (bf16_t)((u + 0x7FFFu + ((u >> 16) & 1u)) >> 16);  // RNE
}
__device__ __forceinline__ ushort2 pk_f2bf(float a, float b) {
    __hip_bfloat162 h2 = __float22bfloat162_rn(float2{a, b});  // v_cvt_pk_bf16_f32
    union { __hip_bfloat162 h; ushort2 u; } u;
    u.h = h2;
    return u.u;
}

// ---------------- CSR build (R9-verified) ----------------

// blocks [0, eblocks): histogram of dst.  blocks [eblocks, eblocks+1344): weight convert.
__global__ void hist_and_convert(
    const int* __restrict__ dst, int E, int eblocks, int* __restrict__ deg,
    const float* __restrict__ w0, const float* __restrict__ w1, const float* __restrict__ w2,
    const float* __restrict__ w3, const float* __restrict__ w4,
    const float* __restrict__ w5, const float* __restrict__ w6,
    const float* __restrict__ wr2, const float* __restrict__ br2,
    bf16_t* __restrict__ t0, bf16_t* __restrict__ t1, bf16_t* __restrict__ t2,
    bf16_t* __restrict__ t3, bf16_t* __restrict__ t4,
    bf16_t* __restrict__ t5, bf16_t* __restrict__ t6,
    bf16_t* __restrict__ teff, float* __restrict__ b_eff)
{
    int t = threadIdx.x;
    if ((int)blockIdx.x < eblocks) {
        int e = blockIdx.x * 256 + t;
        if (e < E) atomicAdd(&deg[dst[e]], 1);
        return;
    }
    int b = blockIdx.x - eblocks;
    const float* W; bf16_t* T; int K, Nc, lb;
    if (b < 384) {
        int g = b / 128; lb = b - g * 128;
        W = g == 0 ? w0 : (g == 1 ? w1 : w2);
        T = g == 0 ? t0 : (g == 1 ? t1 : t2);
        K = 128; Nc = 256;
    } else if (b < 896) {
        int g = (b - 384) / 256; lb = (b - 384) - g * 256;
        W = g == 0 ? w3 : w4; T = g == 0 ? t3 : t4;
        K = 256; Nc = 256;
    } else if (b < 1280) {
        int g = (b - 896) / 192; lb = (b - 896) - g * 192;
        W = g == 0 ? w5 : w6; T = g == 0 ? t5 : t6;
        K = 256; Nc = 160;
    } else {
        lb = b - 1280;
        int idx = lb * 256 + t;          // 64*256 = 16384 elems
        int n = idx >> 8, k = idx & 255;
        float v = 0.f;
        if (n < 40)
            v = 0.25f * (wr2[(size_t)k * 160 + n] + wr2[(size_t)k * 160 + 40 + n] +
                         wr2[(size_t)k * 160 + 80 + n] + wr2[(size_t)k * 160 + 120 + n]);
        teff[idx] = f2bf(v);
        if (lb == 0 && t < 40)
            b_eff[t] = 0.25f * (br2[t] + br2[40 + t] + br2[80 + t] + br2[120 + t]);
        return;
    }
    int idx = lb * 256 + t;
    int n = idx / K, k = idx - n * K;
    float v = (n < Nc) ? W[(size_t)k * Nc + n] : 0.f;
    T[idx] = f2bf(v);
}

__global__ void deg_chunk_sum(const int* __restrict__ deg, int n, int* __restrict__ chunk_sums) {
    __shared__ int sm[256];
    int base = blockIdx.x * 1024;
    int s = 0;
    for (int i = threadIdx.x; i < 1024; i += 256) {
        int idx = base + i;
        if (idx < n) s += deg[idx];
    }
    sm[threadIdx.x] = s;
    __syncthreads();
    for (int off = 128; off > 0; off >>= 1) {
        if (threadIdx.x < off) sm[threadIdx.x] += sm[threadIdx.x + off];
        __syncthreads();
    }
    if (threadIdx.x == 0) chunk_sums[blockIdx.x] = sm[0];
}

__global__ void scan_chunk_sums(int* __restrict__ chunk_sums, int nchunks) {
    __shared__ int sm[256];
    int t = threadIdx.x;
    if (t < nchunks) sm[t] = chunk_sums[t];
    __syncthreads();
    if (t == 0) {
        int run = 0;
        for (int i = 0; i < nchunks; i++) { int v = sm[i]; sm[i] = run; run += v; }
    }
    __syncthreads();
    if (t < nchunks) chunk_sums[t] = sm[t];
}

__global__ void scan_write(const int* __restrict__ deg, int n,
                           const int* __restrict__ chunk_sums,
                           int* __restrict__ row_start, int Etot) {
    int base = blockIdx.x * 1024;
    int t = threadIdx.x;
    int v[4];
    int tsum = 0;
#pragma unroll
    for (int j = 0; j < 4; j++) {
        int idx = base + t * 4 + j;
        v[j] = (idx < n) ? deg[idx] : 0;
        tsum += v[j];
    }
    __shared__ int sm[256];
    sm[t] = tsum;
    __syncthreads();
    for (int off = 1; off < 256; off <<= 1) {
        int x = (t >= off) ? sm[t - off] : 0;
        __syncthreads();
        sm[t] += x;
        __syncthreads();
    }
    int excl = sm[t] - tsum + chunk_sums[blockIdx.x];
#pragma unroll
    for (int j = 0; j < 4; j++) {
        int idx = base + t * 4 + j;
        if (idx < n) row_start[idx] = excl;
        excl += v[j];
    }
    if (blockIdx.x == 0 && t == 0) row_start[n] = Etot;
}

__global__ void scatter_edges(const int* __restrict__ dst, const int* __restrict__ src, int E,
                              const int* __restrict__ row_start,
                              int* __restrict__ fill, int* __restrict__ src_sorted) {
    int e = blockIdx.x * 256 + threadIdx.x;
    if (e < E) {
        int d_ = dst[e];
        int pos = row_start[d_] + atomicAdd(&fill[d_], 1);
        src_sorted[pos] = src[e];
    }
}

// ---------------- single-A-stage multi-output MFMA GEMM (R14 config) ----------------

template <typename TA, int NOUT, int KTOT, int NPAD, bool SPLIT40, bool HAS_EFF>
__global__ __launch_bounds__(256) void gemm_lds(
    const TA* __restrict__ A,
    const bf16_t* __restrict__ Wt0, const bf16_t* __restrict__ Wt1, const bf16_t* __restrict__ Wt2,
    const float* __restrict__ bias0, const float* __restrict__ bias1, const float* __restrict__ bias2,
    bf16_t* __restrict__ C0, bf16_t* __restrict__ C1, bf16_t* __restrict__ C2,
    const bf16_t* __restrict__ Wte, const float* __restrict__ biase, float* __restrict__ Ce,
    int M, int Nc)
{
    constexpr int LSTR = KTOT + 8;     // stage row stride
    constexpr int ESTR = 38;           // epilogue row stride
    constexpr int KC = KTOT / 32;
    __shared__ bf16_t As[64 * LSTR];
    __shared__ bf16_t Ep[4 * 64 * ESTR];

    int tid = threadIdx.x;
    int lane = tid & 63, w = tid >> 6;
    int lm = lane & 15, lq = lane >> 4;
    int m0 = blockIdx.x * 64;

    const bf16_t* Wts[3] = {Wt0, Wt1, Wt2};
    const float* biases[3] = {bias0, bias1, bias2};
    bf16_t* Cs[3] = {C0, C1, C2};

    // ---- stage A slab (64 rows x KTOT) once ----
    if (sizeof(TA) == 4) {            // KTOT == 128, f32 input
#pragma unroll
        for (int it = 0; it < 4; it++) {
            int idx = tid + it * 256;  // 1024 chunks of 8 floats
            int r = idx >> 4, c = idx & 15;
            int gm = m0 + r; if (gm >= M) gm = M - 1;
            const float* ap = (const float*)A + (size_t)gm * KTOT + c * 8;
            float4 lo = *(const float4*)ap;
            float4 hi = *(const float4*)(ap + 4);
            ushort2 p0 = pk_f2bf(lo.x, lo.y), p1 = pk_f2bf(lo.z, lo.w);
            ushort2 p2 = pk_f2bf(hi.x, hi.y), p3 = pk_f2bf(hi.z, hi.w);
            bh8 v = { (short)p0.x, (short)p0.y, (short)p1.x, (short)p1.y,
                      (short)p2.x, (short)p2.y, (short)p3.x, (short)p3.y };
            *(bh8*)(As + r * LSTR + c * 8) = v;
        }
    } else {                           // KTOT == 256, bf16 input
#pragma unroll
        for (int it = 0; it < 8; it++) {
            int idx = tid + it * 256;  // 2048 chunks of 8 bf16
            int r = idx >> 5, c = idx & 31;
            int gm = m0 + r; if (gm >= M) gm = M - 1;
            bh8 v = *(const bh8*)((const bf16_t*)A + (size_t)gm * KTOT + c * 8);
            *(bh8*)(As + r * LSTR + c * 8) = v;
        }
    }
    __syncthreads();   // the ONLY barrier

    bf16_t* ep = Ep + w * (64 * ESTR);
    constexpr int NCHUNK = (NPAD + 127) / 128;

#pragma unroll
    for (int chunk = 0; chunk < NCHUNK; chunk++) {
        int n0 = chunk * 128 + w * 32;
        if (n0 >= NPAD) continue;      // no barriers inside -> safe

        int boff[NOUT][2];
#pragma unroll
        for (int o = 0; o < NOUT; o++)
#pragma unroll
            for (int nt = 0; nt < 2; nt++)
                boff[o][nt] = (n0 + nt * 16 + lm) * KTOT + lq * 8;

        f32x4 acc[NOUT][4][2];
#pragma unroll
        for (int o = 0; o < NOUT; o++)
#pragma unroll
            for (int i = 0; i < 4; i++)
#pragma unroll
                for (int j = 0; j < 2; j++)
                    acc[o][i][j] = (f32x4){0.f, 0.f, 0.f, 0.f};

        bh8 bf_cur[NOUT][2], bf_nxt[NOUT][2];
#pragma unroll
        for (int o = 0; o < NOUT; o++)
#pragma unroll
            for (int nt = 0; nt < 2; nt++)
                bf_cur[o][nt] = *(const bh8*)(Wts[o] + boff[o][nt]);

#pragma unroll
        for (int kc = 0; kc < KC; kc++) {
            if (kc + 1 < KC) {
#pragma unroll
                for (int o = 0; o < NOUT; o++)
#pragma unroll
                    for (int nt = 0; nt < 2; nt++)
                        bf_nxt[o][nt] = *(const bh8*)(Wts[o] + boff[o][nt] + (kc + 1) * 32);
            }
            bh8 af[4];
#pragma unroll
            for (int mt = 0; mt < 4; mt++)
                af[mt] = *(const bh8*)(As + (mt * 16 + lm) * LSTR + kc * 32 + lq * 8);
#pragma unroll
            for (int o = 0; o < NOUT; o++)
#pragma unroll
                for (int mt = 0; mt < 4; mt++)
#pragma unroll
                    for (int nt = 0; nt < 2; nt++)
                        acc[o][mt][nt] = __builtin_amdgcn_mfma_f32_16x16x32_bf16(af[mt], bf_cur[o][nt], acc[o][mt][nt], 0, 0, 0);
            if (kc + 1 < KC) {
#pragma unroll
                for (int o = 0; o < NOUT; o++)
#pragma unroll
                    for (int nt = 0; nt < 2; nt++)
                        bf_cur[o][nt] = bf_nxt[o][nt];
            }
        }

        // ---- per-wave epilogue: private LDS tile -> full-line global stores ----
#pragma unroll
        for (int o = 0; o < NOUT; o++) {
#pragma unroll
            for (int nt = 0; nt < 2; nt++) {
                int gn = n0 + nt * 16 + lm;
                float bv = (gn < Nc) ? biases[o][gn] : 0.f;
#pragma unroll
                for (int mt = 0; mt < 4; mt++)
#pragma unroll
                    for (int r = 0; r < 4; r++)
                        ep[(mt * 16 + lq * 4 + r) * ESTR + nt * 16 + lm] = f2bf(acc[o][mt][nt][r] + bv);
            }
#pragma unroll
            for (int it = 0; it < 4; it++) {
                int row = it * 16 + (lane >> 2);
                int cc = (lane & 3) * 8;
                bh8 v = *(const bh8*)(ep + row * ESTR + cc);
                int gm = m0 + row;
                int cg = n0 + cc;
                if (gm < M && cg < Nc) {
                    size_t cb = SPLIT40 ? (size_t)(cg + 24 * (cg / 40)) : (size_t)cg;
                    size_t rs = SPLIT40 ? 256 : (size_t)Nc;
                    *(bh8*)(Cs[o] + (size_t)gm * rs + cb) = v;
                }
            }
        }
    }

    // ---- folded-residual pass (waves 0-1), reuses LDS A ----
    if (HAS_EFF && w < 2) {
        int beoff[2];
#pragma unroll
        for (int nt = 0; nt < 2; nt++)
            beoff[nt] = (w * 32 + nt * 16 + lm) * KTOT + lq * 8;
        f32x4 acc_e[4][2];
#pragma unroll
        for (int i = 0; i < 4; i++)
#pragma unroll
            for (int j = 0; j < 2; j++)
                acc_e[i][j] = (f32x4){0.f, 0.f, 0.f, 0.f};
#pragma unroll
        for (int kc = 0; kc < KC; kc++) {
            bh8 af[4];
#pragma unroll
            for (int mt = 0; mt < 4; mt++)
                af[mt] = *(const bh8*)(As + (mt * 16 + lm) * LSTR + kc * 32 + lq * 8);
            bh8 be[2];
#pragma unroll
            for (int nt = 0; nt < 2; nt++)
                be[nt] = *(const bh8*)(Wte + beoff[nt] + kc * 32);
#pragma unroll
            for (int mt = 0; mt < 4; mt++)
#pragma unroll
                for (int nt = 0; nt < 2; nt++)
                    acc_e[mt][nt] = __builtin_amdgcn_mfma_f32_16x16x32_bf16(af[mt], be[nt], acc_e[mt][nt], 0, 0, 0);
        }
#pragma unroll
        for (int nt = 0; nt < 2; nt++) {
            int gn = w * 32 + nt * 16 + lm;
            if (gn >= 40) continue;
            float bv = biase[gn];
#pragma unroll
            for (int mt = 0; mt < 4; mt++)
#pragma unroll
                for (int r = 0; r < 4; r++) {
                    int gm = m0 + mt * 16 + lq * 4 + r;
                    if (gm < M) Ce[(size_t)gm * 40 + gn] = acc_e[mt][nt][r] + bv;
                }
        }
    }
}

// ---------------- GATv2 aggregation: QUARTER-WAVE per node, unroll-4, 2 chains ----------------
// All 8 gathers for 4 edges issued up-front (8 loads in flight), then per-edge
// consume; fine-grained vmcnt lets later loads stay outstanding.

__device__ __forceinline__ void us8_to_f(const us8 v, float* h) {
#pragma unroll
    for (int j = 0; j < 8; j++) h[j] = bf2f(v[j]);
}

__device__ __forceinline__ float edge_logit16(const float h[16], const float hdf[16], const float at[16]) {
    float p = 0.f;
#pragma unroll
    for (int j = 0; j < 16; j++) {
        float q = h[j] + hdf[j];
        p += fmaxf(q, SLOPE * q) * at[j];
    }
    p += __shfl_xor(p, 1, 64);
    p += __shfl_xor(p, 2, 64);
    return p;
}

template <int DVALID, bool FINAL, bool RES_INPLACE>
__global__ __launch_bounds__(256) void gat_agg_quarter(
    const bf16_t* __restrict__ hs, const bf16_t* __restrict__ hd,
    const float* __restrict__ attn,
    const int* __restrict__ row_start, const int* __restrict__ src_sorted,
    bf16_t* __restrict__ P, float* __restrict__ out_final, int N)
{
    int w = threadIdx.x >> 6, lane = threadIdx.x & 63;
    int q = lane >> 4, ql = lane & 15;
    int n = blockIdx.x * 16 + w * 4 + q;
    if (n >= N) return;
    int f0 = ql * 16;         // padded feature base
    int h = ql >> 2;          // head
    int dp = (ql & 3) * 16;   // d within head (padded)

    float at[16], hdf[16];
#pragma unroll
    for (int j = 0; j < 16; j++)
        at[j] = (dp + j < DVALID) ? attn[h * DVALID + dp + j] : 0.f;
    {
        us8 a = *(const us8*)(hd + (unsigned)(n * 256 + f0));
        us8 b = *(const us8*)(hd + (unsigned)(n * 256 + f0 + 8));
        us8_to_f(a, hdf); us8_to_f(b, hdf + 8);
    }

    // per-node proxy center: logit at hs=0 (keeps exp args small; logits bounded)
    float pc;
    {
        float p = 0.f;
#pragma unroll
        for (int j = 0; j < 16; j++) {
            float qq = hdf[j];
            p += fmaxf(qq, SLOPE * qq) * at[j];
        }
        p += __shfl_xor(p, 1, 64);
        p += __shfl_xor(p, 2, 64);
        pc = p;
    }

    int s = row_start[n], e = row_start[n + 1];

    float cl0 = 0.f, cl1 = 0.f;
    float ca0[16] = {}, ca1[16] = {};

    int i = s;
    for (; i + 4 <= e; i += 4) {
        int sn0 = src_sorted[i], sn1 = src_sorted[i + 1];
        int sn2 = src_sorted[i + 2], sn3 = src_sorted[i + 3];
        // issue all 8 gathers up-front
        us8 r0a = *(const us8*)(hs + (unsigned)(sn0 * 256 + f0));
        us8 r0b = *(const us8*)(hs + (unsigned)(sn0 * 256 + f0 + 8));
        us8 r1a = *(const us8*)(hs + (unsigned)(sn1 * 256 + f0));
        us8 r1b = *(const us8*)(hs + (unsigned)(sn1 * 256 + f0 + 8));
        us8 r2a = *(const us8*)(hs + (unsigned)(sn2 * 256 + f0));
        us8 r2b = *(const us8*)(hs + (unsigned)(sn2 * 256 + f0 + 8));
        us8 r3a = *(const us8*)(hs + (unsigned)(sn3 * 256 + f0));
        us8 r3b = *(const us8*)(hs + (unsigned)(sn3 * 256 + f0 + 8));
        {
            float h0[16];
            us8_to_f(r0a, h0); us8_to_f(r0b, h0 + 8);
            float w0 = __expf(edge_logit16(h0, hdf, at) - pc);
            cl0 += w0;
#pragma unroll
            for (int j = 0; j < 16; j++) ca0[j] += w0 * h0[j];
        }
        {
            float h1[16];
            us8_to_f(r1a, h1); us8_to_f(r1b, h1 + 8);
            float w1 = __expf(edge_logit16(h1, hdf, at) - pc);
            cl1 += w1;
#pragma unroll
            for (int j = 0; j < 16; j++) ca1[j] += w1 * h1[j];
        }
        {
            float h2[16];
            us8_to_f(r2a, h2); us8_to_f(r2b, h2 + 8);
            float w2 = __expf(edge_logit16(h2, hdf, at) - pc);
            cl0 += w2;
#pragma unroll
            for (int j = 0; j < 16; j++) ca0[j] += w2 * h2[j];
        }
        {
            float h3[16];
            us8_to_f(r3a, h3); us8_to_f(r3b, h3 + 8);
            float w3 = __expf(edge_logit16(h3, hdf, at) - pc);
            cl1 += w3;
#pragma unroll
            for (int j = 0; j < 16; j++) ca1[j] += w3 * h3[j];
        }
    }
    for (; i < e; i++) {
        int sn0 = src_sorted[i];
        us8 r0a = *(const us8*)(hs + (unsigned)(sn0 * 256 + f0));
        us8 r0b = *(const us8*)(hs + (unsigned)(sn0 * 256 + f0 + 8));
        float h0[16];
        us8_to_f(r0a, h0); us8_to_f(r0b, h0 + 8);
        float w0 = __expf(edge_logit16(h0, hdf, at) - pc);
        cl0 += w0;
#pragma unroll
        for (int j = 0; j < 16; j++) ca0[j] += w0 * h0[j];
    }

    float v[16] = {};
    if (e > s) {
        float inv = 1.f / (cl0 + cl1);
#pragma unroll
        for (int j = 0; j < 16; j++)
            v[j] = (ca0[j] + ca1[j]) * inv;
    }

    if (FINAL) {
        // head-sum: lanes ql, ql^4, ql^8, ql^12 hold the same d-range across heads
#pragma unroll
        for (int j = 0; j < 16; j++) {
            v[j] += __shfl_xor(v[j], 4, 64);
            v[j] += __shfl_xor(v[j], 8, 64);
        }
        if (h == 0) {
#pragma unroll
            for (int jj = 0; jj < 16; jj += 4) {
                if (dp + jj < DVALID) {   // DVALID % 4 == 0 -> whole float4 valid
                    float* op = out_final + (unsigned)(n * DVALID + dp + jj);
                    float4 cur = *(float4*)op;
                    cur.x += 0.25f * v[jj];
                    cur.y += 0.25f * v[jj + 1];
                    cur.z += 0.25f * v[jj + 2];
                    cur.w += 0.25f * v[jj + 3];
                    *(float4*)op = cur;
                }
            }
        }
    } else {
        unsigned oi = (unsigned)(n * 256 + f0);
        if (RES_INPLACE) {
            us8 pa = *(const us8*)(P + oi);
            us8 pb = *(const us8*)(P + oi + 8);
#pragma unroll
            for (int j = 0; j < 8; j++) {
                v[j] += bf2f(pa[j]);
                v[8 + j] += bf2f(pb[j]);
            }
        }
        us8 oa, ob;
#pragma unroll
        for (int j = 0; j < 8; j++) {
            oa[j] = f2bf(v[j]);
            ob[j] = f2bf(v[8 + j]);
        }
        *(us8*)(P + oi) = oa;
        *(us8*)(P + oi + 8) = ob;
    }
}

// ---------------- launch ----------------

extern "C" void kernel_launch(void* const* d_in, const int* in_sizes, int n_in,
                              void* d_out, int out_size, void* d_ws, size_t ws_size,
                              hipStream_t stream) {
    const float* x0    = (const float*)d_in[0];
    const int*   src   = (const int*)d_in[1];
    const int*   dst   = (const int*)d_in[2];
    const float* w_src0 = (const float*)d_in[3];  const float* b_src0 = (const float*)d_in[4];
    const float* w_dst0 = (const float*)d_in[5];  const float* b_dst0 = (const float*)d_in[6];
    const float* attn0  = (const float*)d_in[7];
    const float* w_res0 = (const float*)d_in[8];  const float* b_res0 = (const float*)d_in[9];
    const float* w_src1 = (const float*)d_in[10]; const float* b_src1 = (const float*)d_in[11];
    const float* w_dst1 = (const float*)d_in[12]; const float* b_dst1 = (const float*)d_in[13];
    const float* attn1  = (const float*)d_in[14];
    const float* w_src2 = (const float*)d_in[15]; const float* b_src2 = (const float*)d_in[16];
    const float* w_dst2 = (const float*)d_in[17]; const float* b_dst2 = (const float*)d_in[18];
    const float* attn2  = (const float*)d_in[19];
    const float* w_res2 = (const float*)d_in[20]; const float* b_res2 = (const float*)d_in[21];

    const int N = in_sizes[0] / 128;   // 50000
    const int E = in_sizes[1];         // 400000
    float* out = (float*)d_out;
    (void)n_in; (void)out_size; (void)ws_size;

    // ---- workspace (~80 MB) ----
    char* ws = (char*)d_ws;
    size_t off = 0;
    auto alloc = [&](size_t bytes) {
        void* q = ws + off;
        off = (off + bytes + 255) & ~(size_t)255;
        return q;
    };
    int* deg        = (int*)alloc((size_t)2 * N * 4);
    int* fill       = deg + N;
    int* row_start  = (int*)alloc((size_t)(N + 1) * 4);
    int* chunk_sums = (int*)alloc(256 * 4);
    int* src_sorted = (int*)alloc((size_t)E * 4);
    bf16_t* t_src0 = (bf16_t*)alloc(256 * 128 * 2);
    bf16_t* t_dst0 = (bf16_t*)alloc(256 * 128 * 2);
    bf16_t* t_res0 = (bf16_t*)alloc(256 * 128 * 2);
    bf16_t* t_src1 = (bf16_t*)alloc(256 * 256 * 2);
    bf16_t* t_dst1 = (bf16_t*)alloc(256 * 256 * 2);
    bf16_t* t_src2 = (bf16_t*)alloc(192 * 256 * 2);
    bf16_t* t_dst2 = (bf16_t*)alloc(192 * 256 * 2);
    bf16_t* t_eff  = (bf16_t*)alloc(64 * 256 * 2);
    float*  b_eff  = (float*)alloc(64 * 4);
    const size_t elems = (size_t)N * 256;
    bf16_t* P  = (bf16_t*)alloc(elems * 2);
    bf16_t* HS = (bf16_t*)alloc(elems * 2);
    bf16_t* HD = (bf16_t*)alloc(elems * 2);

    // ---- CSR build + weight conversion ----
    hipMemsetAsync(deg, 0, (size_t)2 * N * 4, stream);
    int eblocks = (E + 255) / 256;
    int nchunks = (N + 1023) / 1024;
    hipLaunchKernelGGL(hist_and_convert, dim3(eblocks + 1344), dim3(256), 0, stream,
                       dst, E, eblocks, deg,
                       w_src0, w_dst0, w_res0, w_src1, w_dst1, w_src2, w_dst2, w_res2, b_res2,
                       t_src0, t_dst0, t_res0, t_src1, t_dst1, t_src2, t_dst2, t_eff, b_eff);
    hipLaunchKernelGGL(deg_chunk_sum, dim3(nchunks), dim3(256), 0, stream, deg, N, chunk_sums);
    hipLaunchKernelGGL(scan_chunk_sums, dim3(1), dim3(256), 0, stream, chunk_sums, nchunks);
    hipLaunchKernelGGL(scan_write, dim3(nchunks), dim3(256), 0, stream, deg, N, chunk_sums, row_start, E);
    hipLaunchKernelGGL(scatter_edges, dim3(eblocks), dim3(256), 0, stream, dst, src, E, row_start, fill, src_sorted);

    dim3 blk(256);
    int mtiles = (N + 63) / 64;        // 782
    int ab = (N + 15) / 16;            // 3125 (quarter-wave-per-node agg)

    // ---- Layer 0: fused hs|hd|res from x0; agg adds onto res (in P) ----
    hipLaunchKernelGGL((gemm_lds<float, 3, 128, 256, false, false>), dim3(mtiles), blk, 0, stream,
                       x0, t_src0, t_dst0, t_res0, b_src0, b_dst0, b_res0,
                       HS, HD, P,
                       (const bf16_t*)nullptr, (const float*)nullptr, (float*)nullptr,
                       N, 256);
    hipLaunchKernelGGL((gat_agg_quarter<64, false, true>), dim3(ab), blk, 0, stream,
                       HS, HD, attn0, row_start, src_sorted, P, (float*)nullptr, N);

    // ---- Layer 1: fused hs|hd from P; identity residual in-place ----
    hipLaunchKernelGGL((gemm_lds<bf16_t, 2, 256, 256, false, false>), dim3(mtiles), blk, 0, stream,
                       P, t_src1, t_dst1, (const bf16_t*)nullptr, b_src1, b_dst1, (const float*)nullptr,
                       HS, HD, (bf16_t*)nullptr,
                       (const bf16_t*)nullptr, (const float*)nullptr, (float*)nullptr,
                       N, 256);
    hipLaunchKernelGGL((gat_agg_quarter<64, false, true>), dim3(ab), blk, 0, stream,
                       HS, HD, attn1, row_start, src_sorted, P, (float*)nullptr, N);

    // ---- Layer 2: fused hs|hd (SPLIT40) + eff residual (f32 -> out); FINAL agg accumulates ----
    hipLaunchKernelGGL((gemm_lds<bf16_t, 2, 256, 192, true, true>), dim3(mtiles), blk, 0, stream,
                       P, t_src2, t_dst2, (const bf16_t*)nullptr, b_src2, b_dst2, (const float*)nullptr,
                       HS, HD, (bf16_t*)nullptr,
                       t_eff, b_eff, out,
                       N, 160);
    hipLaunchKernelGGL((gat_agg_quarter<40, true, false>), dim3(ab), blk, 0, stream,
                       HS, HD, attn2, row_start, src_sorted, (bf16_t*)nullptr, out, N);
}

// Round 16
// 432.426 us; speedup vs baseline: 1.0842x; 1.0842x over previous
//
#include <hip/hip_runtime.h>
#include <hip/hip_bf16.h>
#include <math.h>

// N=50000, E=400000, F_IN=128, HID=64, OUT=40, H=4
#define SLOPE 0.2f

typedef unsigned short bf16_t;
typedef short bh8 __attribute__((ext_vector_type(8)));
typedef unsigned short us8 __attribute__((ext_vector_type(8)));
typedef float f32x4 __attribute__((ext_vector_type(4)));

__device__ __forceinline__ float bf2f(bf16_t x) {
    return __uint_as_float((unsigned)x << 16);
}
__device__ __forceinline__ bf16_t f2bf(float v) {
    unsigned u = __float_as_uint(v);
    return (bf16_t)((u + 0x7FFFu + ((u >> 16) & 1u)) >> 16);  // RNE
}
__device__ __forceinline__ ushort2 pk_f2bf(float a, float b) {
    __hip_bfloat162 h2 = __float22bfloat162_rn(float2{a, b});  // v_cvt_pk_bf16_f32
    union { __hip_bfloat162 h; ushort2 u; } u;
    u.h = h2;
    return u.u;
}

// ---------------- fused histogram + weight conversion (R15-verified merge) ----------------
// blocks [0, eblocks): histogram of dst.  blocks [eblocks, eblocks+1344): weight convert.

__global__ void hist_and_convert(
    const int* __restrict__ dst, int E, int eblocks, int* __restrict__ deg,
    const float* __restrict__ w0, const float* __restrict__ w1, const float* __restrict__ w2,
    const float* __restrict__ w3, const float* __restrict__ w4,
    const float* __restrict__ w5, const float* __restrict__ w6,
    const float* __restrict__ wr2, const float* __restrict__ br2,
    bf16_t* __restrict__ t0, bf16_t* __restrict__ t1, bf16_t* __restrict__ t2,
    bf16_t* __restrict__ t3, bf16_t* __restrict__ t4,
    bf16_t* __restrict__ t5, bf16_t* __restrict__ t6,
    bf16_t* __restrict__ teff, float* __restrict__ b_eff)
{
    int t = threadIdx.x;
    if ((int)blockIdx.x < eblocks) {
        int e = blockIdx.x * 256 + t;
        if (e < E) atomicAdd(&deg[dst[e]], 1);
        return;
    }
    int b = blockIdx.x - eblocks;
    const float* W; bf16_t* T; int K, Nc, lb;
    if (b < 384) {
        int g = b / 128; lb = b - g * 128;
        W = g == 0 ? w0 : (g == 1 ? w1 : w2);
        T = g == 0 ? t0 : (g == 1 ? t1 : t2);
        K = 128; Nc = 256;
    } else if (b < 896) {
        int g = (b - 384) / 256; lb = (b - 384) - g * 256;
        W = g == 0 ? w3 : w4; T = g == 0 ? t3 : t4;
        K = 256; Nc = 256;
    } else if (b < 1280) {
        int g = (b - 896) / 192; lb = (b - 896) - g * 192;
        W = g == 0 ? w5 : w6; T = g == 0 ? t5 : t6;
        K = 256; Nc = 160;
    } else {
        lb = b - 1280;
        int idx = lb * 256 + t;          // 64*256 = 16384 elems
        int n = idx >> 8, k = idx & 255;
        float v = 0.f;
        if (n < 40)
            v = 0.25f * (wr2[(size_t)k * 160 + n] + wr2[(size_t)k * 160 + 40 + n] +
                         wr2[(size_t)k * 160 + 80 + n] + wr2[(size_t)k * 160 + 120 + n]);
        teff[idx] = f2bf(v);
        if (lb == 0 && t < 40)
            b_eff[t] = 0.25f * (br2[t] + br2[40 + t] + br2[80 + t] + br2[120 + t]);
        return;
    }
    int idx = lb * 256 + t;
    int n = idx / K, k = idx - n * K;
    float v = (n < Nc) ? W[(size_t)k * Nc + n] : 0.f;
    T[idx] = f2bf(v);
}

// ---------------- CSR scan (R9-verified) ----------------

__global__ void deg_chunk_sum(const int* __restrict__ deg, int n, int* __restrict__ chunk_sums) {
    __shared__ int sm[256];
    int base = blockIdx.x * 1024;
    int s = 0;
    for (int i = threadIdx.x; i < 1024; i += 256) {
        int idx = base + i;
        if (idx < n) s += deg[idx];
    }
    sm[threadIdx.x] = s;
    __syncthreads();
    for (int off = 128; off > 0; off >>= 1) {
        if (threadIdx.x < off) sm[threadIdx.x] += sm[threadIdx.x + off];
        __syncthreads();
    }
    if (threadIdx.x == 0) chunk_sums[blockIdx.x] = sm[0];
}

__global__ void scan_chunk_sums(int* __restrict__ chunk_sums, int nchunks) {
    __shared__ int sm[256];
    int t = threadIdx.x;
    if (t < nchunks) sm[t] = chunk_sums[t];
    __syncthreads();
    if (t == 0) {
        int run = 0;
        for (int i = 0; i < nchunks; i++) { int v = sm[i]; sm[i] = run; run += v; }
    }
    __syncthreads();
    if (t < nchunks) chunk_sums[t] = sm[t];
}

__global__ void scan_write(const int* __restrict__ deg, int n,
                           const int* __restrict__ chunk_sums,
                           int* __restrict__ row_start, int Etot) {
    int base = blockIdx.x * 1024;
    int t = threadIdx.x;
    int v[4];
    int tsum = 0;
#pragma unroll
    for (int j = 0; j < 4; j++) {
        int idx = base + t * 4 + j;
        v[j] = (idx < n) ? deg[idx] : 0;
        tsum += v[j];
    }
    __shared__ int sm[256];
    sm[t] = tsum;
    __syncthreads();
    for (int off = 1; off < 256; off <<= 1) {
        int x = (t >= off) ? sm[t - off] : 0;
        __syncthreads();
        sm[t] += x;
        __syncthreads();
    }
    int excl = sm[t] - tsum + chunk_sums[blockIdx.x];
#pragma unroll
    for (int j = 0; j < 4; j++) {
        int idx = base + t * 4 + j;
        if (idx < n) row_start[idx] = excl;
        excl += v[j];
    }
    if (blockIdx.x == 0 && t == 0) row_start[n] = Etot;
}

__global__ void scatter_edges(const int* __restrict__ dst, const int* __restrict__ src, int E,
                              const int* __restrict__ row_start,
                              int* __restrict__ fill, int* __restrict__ src_sorted) {
    int e = blockIdx.x * 256 + threadIdx.x;
    if (e < E) {
        int d_ = dst[e];
        int pos = row_start[d_] + atomicAdd(&fill[d_], 1);
        src_sorted[pos] = src[e];
    }
}

// ---------------- single-A-stage multi-output MFMA GEMM (R14 config) ----------------

template <typename TA, int NOUT, int KTOT, int NPAD, bool SPLIT40, bool HAS_EFF>
__global__ __launch_bounds__(256) void gemm_lds(
    const TA* __restrict__ A,
    const bf16_t* __restrict__ Wt0, const bf16_t* __restrict__ Wt1, const bf16_t* __restrict__ Wt2,
    const float* __restrict__ bias0, const float* __restrict__ bias1, const float* __restrict__ bias2,
    bf16_t* __restrict__ C0, bf16_t* __restrict__ C1, bf16_t* __restrict__ C2,
    const bf16_t* __restrict__ Wte, const float* __restrict__ biase, float* __restrict__ Ce,
    int M, int Nc)
{
    constexpr int LSTR = KTOT + 8;     // stage row stride
    constexpr int ESTR = 38;           // epilogue row stride
    constexpr int KC = KTOT / 32;
    __shared__ bf16_t As[64 * LSTR];
    __shared__ bf16_t Ep[4 * 64 * ESTR];

    int tid = threadIdx.x;
    int lane = tid & 63, w = tid >> 6;
    int lm = lane & 15, lq = lane >> 4;
    int m0 = blockIdx.x * 64;

    const bf16_t* Wts[3] = {Wt0, Wt1, Wt2};
    const float* biases[3] = {bias0, bias1, bias2};
    bf16_t* Cs[3] = {C0, C1, C2};

    // ---- stage A slab (64 rows x KTOT) once ----
    if (sizeof(TA) == 4) {            // KTOT == 128, f32 input
#pragma unroll
        for (int it = 0; it < 4; it++) {
            int idx = tid + it * 256;  // 1024 chunks of 8 floats
            int r = idx >> 4, c = idx & 15;
            int gm = m0 + r; if (gm >= M) gm = M - 1;
            const float* ap = (const float*)A + (size_t)gm * KTOT + c * 8;
            float4 lo = *(const float4*)ap;
            float4 hi = *(const float4*)(ap + 4);
            ushort2 p0 = pk_f2bf(lo.x, lo.y), p1 = pk_f2bf(lo.z, lo.w);
            ushort2 p2 = pk_f2bf(hi.x, hi.y), p3 = pk_f2bf(hi.z, hi.w);
            bh8 v = { (short)p0.x, (short)p0.y, (short)p1.x, (short)p1.y,
                      (short)p2.x, (short)p2.y, (short)p3.x, (short)p3.y };
            *(bh8*)(As + r * LSTR + c * 8) = v;
        }
    } else {                           // KTOT == 256, bf16 input
#pragma unroll
        for (int it = 0; it < 8; it++) {
            int idx = tid + it * 256;  // 2048 chunks of 8 bf16
            int r = idx >> 5, c = idx & 31;
            int gm = m0 + r; if (gm >= M) gm = M - 1;
            bh8 v = *(const bh8*)((const bf16_t*)A + (size_t)gm * KTOT + c * 8);
            *(bh8*)(As + r * LSTR + c * 8) = v;
        }
    }
    __syncthreads();   // the ONLY barrier

    bf16_t* ep = Ep + w * (64 * ESTR);
    constexpr int NCHUNK = (NPAD + 127) / 128;

#pragma unroll
    for (int chunk = 0; chunk < NCHUNK; chunk++) {
        int n0 = chunk * 128 + w * 32;
        if (n0 >= NPAD) continue;      // no barriers inside -> safe

        int boff[NOUT][2];
#pragma unroll
        for (int o = 0; o < NOUT; o++)
#pragma unroll
            for (int nt = 0; nt < 2; nt++)
                boff[o][nt] = (n0 + nt * 16 + lm) * KTOT + lq * 8;

        f32x4 acc[NOUT][4][2];
#pragma unroll
        for (int o = 0; o < NOUT; o++)
#pragma unroll
            for (int i = 0; i < 4; i++)
#pragma unroll
                for (int j = 0; j < 2; j++)
                    acc[o][i][j] = (f32x4){0.f, 0.f, 0.f, 0.f};

        bh8 bf_cur[NOUT][2], bf_nxt[NOUT][2];
#pragma unroll
        for (int o = 0; o < NOUT; o++)
#pragma unroll
            for (int nt = 0; nt < 2; nt++)
                bf_cur[o][nt] = *(const bh8*)(Wts[o] + boff[o][nt]);

#pragma unroll
        for (int kc = 0; kc < KC; kc++) {
            if (kc + 1 < KC) {
#pragma unroll
                for (int o = 0; o < NOUT; o++)
#pragma unroll
                    for (int nt = 0; nt < 2; nt++)
                        bf_nxt[o][nt] = *(const bh8*)(Wts[o] + boff[o][nt] + (kc + 1) * 32);
            }
            bh8 af[4];
#pragma unroll
            for (int mt = 0; mt < 4; mt++)
                af[mt] = *(const bh8*)(As + (mt * 16 + lm) * LSTR + kc * 32 + lq * 8);
#pragma unroll
            for (int o = 0; o < NOUT; o++)
#pragma unroll
                for (int mt = 0; mt < 4; mt++)
#pragma unroll
                    for (int nt = 0; nt < 2; nt++)
                        acc[o][mt][nt] = __builtin_amdgcn_mfma_f32_16x16x32_bf16(af[mt], bf_cur[o][nt], acc[o][mt][nt], 0, 0, 0);
            if (kc + 1 < KC) {
#pragma unroll
                for (int o = 0; o < NOUT; o++)
#pragma unroll
                    for (int nt = 0; nt < 2; nt++)
                        bf_cur[o][nt] = bf_nxt[o][nt];
            }
        }

        // ---- per-wave epilogue: private LDS tile -> full-line global stores ----
#pragma unroll
        for (int o = 0; o < NOUT; o++) {
#pragma unroll
            for (int nt = 0; nt < 2; nt++) {
                int gn = n0 + nt * 16 + lm;
                float bv = (gn < Nc) ? biases[o][gn] : 0.f;
#pragma unroll
                for (int mt = 0; mt < 4; mt++)
#pragma unroll
                    for (int r = 0; r < 4; r++)
                        ep[(mt * 16 + lq * 4 + r) * ESTR + nt * 16 + lm] = f2bf(acc[o][mt][nt][r] + bv);
            }
#pragma unroll
            for (int it = 0; it < 4; it++) {
                int row = it * 16 + (lane >> 2);
                int cc = (lane & 3) * 8;
                bh8 v = *(const bh8*)(ep + row * ESTR + cc);
                int gm = m0 + row;
                int cg = n0 + cc;
                if (gm < M && cg < Nc) {
                    size_t cb = SPLIT40 ? (size_t)(cg + 24 * (cg / 40)) : (size_t)cg;
                    size_t rs = SPLIT40 ? 256 : (size_t)Nc;
                    *(bh8*)(Cs[o] + (size_t)gm * rs + cb) = v;
                }
            }
        }
    }

    // ---- folded-residual pass (waves 0-1), reuses LDS A ----
    if (HAS_EFF && w < 2) {
        int beoff[2];
#pragma unroll
        for (int nt = 0; nt < 2; nt++)
            beoff[nt] = (w * 32 + nt * 16 + lm) * KTOT + lq * 8;
        f32x4 acc_e[4][2];
#pragma unroll
        for (int i = 0; i < 4; i++)
#pragma unroll
            for (int j = 0; j < 2; j++)
                acc_e[i][j] = (f32x4){0.f, 0.f, 0.f, 0.f};
#pragma unroll
        for (int kc = 0; kc < KC; kc++) {
            bh8 af[4];
#pragma unroll
            for (int mt = 0; mt < 4; mt++)
                af[mt] = *(const bh8*)(As + (mt * 16 + lm) * LSTR + kc * 32 + lq * 8);
            bh8 be[2];
#pragma unroll
            for (int nt = 0; nt < 2; nt++)
                be[nt] = *(const bh8*)(Wte + beoff[nt] + kc * 32);
#pragma unroll
            for (int mt = 0; mt < 4; mt++)
#pragma unroll
                for (int nt = 0; nt < 2; nt++)
                    acc_e[mt][nt] = __builtin_amdgcn_mfma_f32_16x16x32_bf16(af[mt], be[nt], acc_e[mt][nt], 0, 0, 0);
        }
#pragma unroll
        for (int nt = 0; nt < 2; nt++) {
            int gn = w * 32 + nt * 16 + lm;
            if (gn >= 40) continue;
            float bv = biase[gn];
#pragma unroll
            for (int mt = 0; mt < 4; mt++)
#pragma unroll
                for (int r = 0; r < 4; r++) {
                    int gm = m0 + mt * 16 + lq * 4 + r;
                    if (gm < M) Ce[(size_t)gm * 40 + gn] = acc_e[mt][nt][r] + bv;
                }
        }
    }
}

// ---------------- GATv2 aggregation: QUARTER-WAVE per node, unroll-2 (R13/R14-verified) ----------------

__device__ __forceinline__ void us8_to_f(const us8 v, float* h) {
#pragma unroll
    for (int j = 0; j < 8; j++) h[j] = bf2f(v[j]);
}

__device__ __forceinline__ float edge_logit16(const float h[16], const float hdf[16], const float at[16]) {
    float p = 0.f;
#pragma unroll
    for (int j = 0; j < 16; j++) {
        float q = h[j] + hdf[j];
        p += fmaxf(q, SLOPE * q) * at[j];
    }
    p += __shfl_xor(p, 1, 64);
    p += __shfl_xor(p, 2, 64);
    return p;
}

template <int DVALID, bool FINAL, bool RES_INPLACE>
__global__ __launch_bounds__(256) void gat_agg_quarter(
    const bf16_t* __restrict__ hs, const bf16_t* __restrict__ hd,
    const float* __restrict__ attn,
    const int* __restrict__ row_start, const int* __restrict__ src_sorted,
    bf16_t* __restrict__ P, float* __restrict__ out_final, int N)
{
    int w = threadIdx.x >> 6, lane = threadIdx.x & 63;
    int q = lane >> 4, ql = lane & 15;
    int n = blockIdx.x * 16 + w * 4 + q;
    if (n >= N) return;
    int f0 = ql * 16;         // padded feature base
    int h = ql >> 2;          // head
    int dp = (ql & 3) * 16;   // d within head (padded)

    float at[16], hdf[16];
#pragma unroll
    for (int j = 0; j < 16; j++)
        at[j] = (dp + j < DVALID) ? attn[h * DVALID + dp + j] : 0.f;
    {
        us8 a = *(const us8*)(hd + (unsigned)(n * 256 + f0));
        us8 b = *(const us8*)(hd + (unsigned)(n * 256 + f0 + 8));
        us8_to_f(a, hdf); us8_to_f(b, hdf + 8);
    }

    // per-node proxy center: logit at hs=0 (keeps exp args small; logits bounded)
    float pc;
    {
        float p = 0.f;
#pragma unroll
        for (int j = 0; j < 16; j++) {
            float qq = hdf[j];
            p += fmaxf(qq, SLOPE * qq) * at[j];
        }
        p += __shfl_xor(p, 1, 64);
        p += __shfl_xor(p, 2, 64);
        pc = p;
    }

    int s = row_start[n], e = row_start[n + 1];

    float cl0 = 0.f, cl1 = 0.f;
    float ca0[16] = {}, ca1[16] = {};

    int i = s;
    for (; i + 2 <= e; i += 2) {
        int sn0 = src_sorted[i], sn1 = src_sorted[i + 1];
        us8 r0a = *(const us8*)(hs + (unsigned)(sn0 * 256 + f0));
        us8 r0b = *(const us8*)(hs + (unsigned)(sn0 * 256 + f0 + 8));
        us8 r1a = *(const us8*)(hs + (unsigned)(sn1 * 256 + f0));
        us8 r1b = *(const us8*)(hs + (unsigned)(sn1 * 256 + f0 + 8));
        float h0[16], h1[16];
        us8_to_f(r0a, h0); us8_to_f(r0b, h0 + 8);
        us8_to_f(r1a, h1); us8_to_f(r1b, h1 + 8);
        float w0 = __expf(edge_logit16(h0, hdf, at) - pc);
        float w1 = __expf(edge_logit16(h1, hdf, at) - pc);
        cl0 += w0; cl1 += w1;
#pragma unroll
        for (int j = 0; j < 16; j++) {
            ca0[j] += w0 * h0[j];
            ca1[j] += w1 * h1[j];
        }
    }
    if (i < e) {
        int sn0 = src_sorted[i];
        us8 r0a = *(const us8*)(hs + (unsigned)(sn0 * 256 + f0));
        us8 r0b = *(const us8*)(hs + (unsigned)(sn0 * 256 + f0 + 8));
        float h0[16];
        us8_to_f(r0a, h0); us8_to_f(r0b, h0 + 8);
        float w0 = __expf(edge_logit16(h0, hdf, at) - pc);
        cl0 += w0;
#pragma unroll
        for (int j = 0; j < 16; j++) ca0[j] += w0 * h0[j];
    }

    float v[16] = {};
    if (e > s) {
        float inv = 1.f / (cl0 + cl1);
#pragma unroll
        for (int j = 0; j < 16; j++)
            v[j] = (ca0[j] + ca1[j]) * inv;
    }

    if (FINAL) {
        // head-sum: lanes ql, ql^4, ql^8, ql^12 hold the same d-range across heads
#pragma unroll
        for (int j = 0; j < 16; j++) {
            v[j] += __shfl_xor(v[j], 4, 64);
            v[j] += __shfl_xor(v[j], 8, 64);
        }
        if (h == 0) {
#pragma unroll
            for (int jj = 0; jj < 16; jj += 4) {
                if (dp + jj < DVALID) {   // DVALID % 4 == 0 -> whole float4 valid
                    float* op = out_final + (unsigned)(n * DVALID + dp + jj);
                    float4 cur = *(float4*)op;
                    cur.x += 0.25f * v[jj];
                    cur.y += 0.25f * v[jj + 1];
                    cur.z += 0.25f * v[jj + 2];
                    cur.w += 0.25f * v[jj + 3];
                    *(float4*)op = cur;
                }
            }
        }
    } else {
        unsigned oi = (unsigned)(n * 256 + f0);
        if (RES_INPLACE) {
            us8 pa = *(const us8*)(P + oi);
            us8 pb = *(const us8*)(P + oi + 8);
#pragma unroll
            for (int j = 0; j < 8; j++) {
                v[j] += bf2f(pa[j]);
                v[8 + j] += bf2f(pb[j]);
            }
        }
        us8 oa, ob;
#pragma unroll
        for (int j = 0; j < 8; j++) {
            oa[j] = f2bf(v[j]);
            ob[j] = f2bf(v[8 + j]);
        }
        *(us8*)(P + oi) = oa;
        *(us8*)(P + oi + 8) = ob;
    }
}

// ---------------- launch ----------------

extern "C" void kernel_launch(void* const* d_in, const int* in_sizes, int n_in,
                              void* d_out, int out_size, void* d_ws, size_t ws_size,
                              hipStream_t stream) {
    const float* x0    = (const float*)d_in[0];
    const int*   src   = (const int*)d_in[1];
    const int*   dst   = (const int*)d_in[2];
    const float* w_src0 = (const float*)d_in[3];  const float* b_src0 = (const float*)d_in[4];
    const float* w_dst0 = (const float*)d_in[5];  const float* b_dst0 = (const float*)d_in[6];
    const float* attn0  = (const float*)d_in[7];
    const float* w_res0 = (const float*)d_in[8];  const float* b_res0 = (const float*)d_in[9];
    const float* w_src1 = (const float*)d_in[10]; const float* b_src1 = (const float*)d_in[11];
    const float* w_dst1 = (const float*)d_in[12]; const float* b_dst1 = (const float*)d_in[13];
    const float* attn1  = (const float*)d_in[14];
    const float* w_src2 = (const float*)d_in[15]; const float* b_src2 = (const float*)d_in[16];
    const float* w_dst2 = (const float*)d_in[17]; const float* b_dst2 = (const float*)d_in[18];
    const float* attn2  = (const float*)d_in[19];
    const float* w_res2 = (const float*)d_in[20]; const float* b_res2 = (const float*)d_in[21];

    const int N = in_sizes[0] / 128;   // 50000
    const int E = in_sizes[1];         // 400000
    float* out = (float*)d_out;
    (void)n_in; (void)out_size; (void)ws_size;

    // ---- workspace (~80 MB) ----
    char* ws = (char*)d_ws;
    size_t off = 0;
    auto alloc = [&](size_t bytes) {
        void* q = ws + off;
        off = (off + bytes + 255) & ~(size_t)255;
        return q;
    };
    int* deg        = (int*)alloc((size_t)2 * N * 4);
    int* fill       = deg + N;
    int* row_start  = (int*)alloc((size_t)(N + 1) * 4);
    int* chunk_sums = (int*)alloc(256 * 4);
    int* src_sorted = (int*)alloc((size_t)E * 4);
    bf16_t* t_src0 = (bf16_t*)alloc(256 * 128 * 2);
    bf16_t* t_dst0 = (bf16_t*)alloc(256 * 128 * 2);
    bf16_t* t_res0 = (bf16_t*)alloc(256 * 128 * 2);
    bf16_t* t_src1 = (bf16_t*)alloc(256 * 256 * 2);
    bf16_t* t_dst1 = (bf16_t*)alloc(256 * 256 * 2);
    bf16_t* t_src2 = (bf16_t*)alloc(192 * 256 * 2);
    bf16_t* t_dst2 = (bf16_t*)alloc(192 * 256 * 2);
    bf16_t* t_eff  = (bf16_t*)alloc(64 * 256 * 2);
    float*  b_eff  = (float*)alloc(64 * 4);
    const size_t elems = (size_t)N * 256;
    bf16_t* P  = (bf16_t*)alloc(elems * 2);
    bf16_t* HS = (bf16_t*)alloc(elems * 2);
    bf16_t* HD = (bf16_t*)alloc(elems * 2);

    // ---- CSR build + weight conversion ----
    hipMemsetAsync(deg, 0, (size_t)2 * N * 4, stream);
    int eblocks = (E + 255) / 256;
    int nchunks = (N + 1023) / 1024;
    hipLaunchKernelGGL(hist_and_convert, dim3(eblocks + 1344), dim3(256), 0, stream,
                       dst, E, eblocks, deg,
                       w_src0, w_dst0, w_res0, w_src1, w_dst1, w_src2, w_dst2, w_res2, b_res2,
                       t_src0, t_dst0, t_res0, t_src1, t_dst1, t_src2, t_dst2, t_eff, b_eff);
    hipLaunchKernelGGL(deg_chunk_sum, dim3(nchunks), dim3(256), 0, stream, deg, N, chunk_sums);
    hipLaunchKernelGGL(scan_chunk_sums, dim3(1), dim3(256), 0, stream, chunk_sums, nchunks);
    hipLaunchKernelGGL(scan_write, dim3(nchunks), dim3(256), 0, stream, deg, N, chunk_sums, row_start, E);
    hipLaunchKernelGGL(scatter_edges, dim3(eblocks), dim3(256), 0, stream, dst, src, E, row_start, fill, src_sorted);

    dim3 blk(256);
    int mtiles = (N + 63) / 64;        // 782
    int ab = (N + 15) / 16;            // 3125 (quarter-wave-per-node agg)

    // ---- Layer 0: fused hs|hd|res from x0; agg adds onto res (in P) ----
    hipLaunchKernelGGL((gemm_lds<float, 3, 128, 256, false, false>), dim3(mtiles), blk, 0, stream,
                       x0, t_src0, t_dst0, t_res0, b_src0, b_dst0, b_res0,
                       HS, HD, P,
                       (const bf16_t*)nullptr, (const float*)nullptr, (float*)nullptr,
                       N, 256);
    hipLaunchKernelGGL((gat_agg_quarter<64, false, true>), dim3(ab), blk, 0, stream,
                       HS, HD, attn0, row_start, src_sorted, P, (float*)nullptr, N);

    // ---- Layer 1: fused hs|hd from P; identity residual in-place ----
    hipLaunchKernelGGL((gemm_lds<bf16_t, 2, 256, 256, false, false>), dim3(mtiles), blk, 0, stream,
                       P, t_src1, t_dst1, (const bf16_t*)nullptr, b_src1, b_dst1, (const float*)nullptr,
                       HS, HD, (bf16_t*)nullptr,
                       (const bf16_t*)nullptr, (const float*)nullptr, (float*)nullptr,
                       N, 256);
    hipLaunchKernelGGL((gat_agg_quarter<64, false, true>), dim3(ab), blk, 0, stream,
                       HS, HD, attn1, row_start, src_sorted, P, (float*)nullptr, N);

    // ---- Layer 2: fused hs|hd (SPLIT40) + eff residual (f32 -> out); FINAL agg accumulates ----
    hipLaunchKernelGGL((gemm_lds<bf16_t, 2, 256, 192, true, true>), dim3(mtiles), blk, 0, stream,
                       P, t_src2, t_dst2, (const bf16_t*)nullptr, b_src2, b_dst2, (const float*)nullptr,
                       HS, HD, (bf16_t*)nullptr,
                       t_eff, b_eff, out,
                       N, 160);
    hipLaunchKernelGGL((gat_agg_quarter<40, true, false>), dim3(ab), blk, 0, stream,
                       HS, HD, attn2, row_start, src_sorted, (bf16_t*)nullptr, out, N);
}

// Round 17
// 419.492 us; speedup vs baseline: 1.1176x; 1.0308x over previous
//
#include <hip/hip_runtime.h>
#include <hip/hip_bf16.h>
#include <math.h>

// N=50000, E=400000, F_IN=128, HID=64, OUT=40, H=4
#define SLOPE 0.2f

typedef unsigned short bf16_t;
typedef short bh8 __attribute__((ext_vector_type(8)));
typedef unsigned short us8 __attribute__((ext_vector_type(8)));
typedef float f32x4 __attribute__((ext_vector_type(4)));

__device__ __forceinline__ float bf2f(bf16_t x) {
    return __uint_as_float((unsigned)x << 16);
}
__device__ __forceinline__ bf16_t f2bf(float v) {
    unsigned u = __float_as_uint(v);
    return (bf16_t)((u + 0x7FFFu + ((u >> 16) & 1u)) >> 16);  // RNE
}
__device__ __forceinline__ ushort2 pk_f2bf(float a, float b) {
    __hip_bfloat162 h2 = __float22bfloat162_rn(float2{a, b});  // v_cvt_pk_bf16_f32
    union { __hip_bfloat162 h; ushort2 u; } u;
    u.h = h2;
    return u.u;
}

// ---------------- fused histogram + weight conversion (R15/R16-verified) ----------------

__global__ void hist_and_convert(
    const int* __restrict__ dst, int E, int eblocks, int* __restrict__ deg,
    const float* __restrict__ w0, const float* __restrict__ w1, const float* __restrict__ w2,
    const float* __restrict__ w3, const float* __restrict__ w4,
    const float* __restrict__ w5, const float* __restrict__ w6,
    const float* __restrict__ wr2, const float* __restrict__ br2,
    bf16_t* __restrict__ t0, bf16_t* __restrict__ t1, bf16_t* __restrict__ t2,
    bf16_t* __restrict__ t3, bf16_t* __restrict__ t4,
    bf16_t* __restrict__ t5, bf16_t* __restrict__ t6,
    bf16_t* __restrict__ teff, float* __restrict__ b_eff)
{
    int t = threadIdx.x;
    if ((int)blockIdx.x < eblocks) {
        int e = blockIdx.x * 256 + t;
        if (e < E) atomicAdd(&deg[dst[e]], 1);
        return;
    }
    int b = blockIdx.x - eblocks;
    const float* W; bf16_t* T; int K, Nc, lb;
    if (b < 384) {
        int g = b / 128; lb = b - g * 128;
        W = g == 0 ? w0 : (g == 1 ? w1 : w2);
        T = g == 0 ? t0 : (g == 1 ? t1 : t2);
        K = 128; Nc = 256;
    } else if (b < 896) {
        int g = (b - 384) / 256; lb = (b - 384) - g * 256;
        W = g == 0 ? w3 : w4; T = g == 0 ? t3 : t4;
        K = 256; Nc = 256;
    } else if (b < 1280) {
        int g = (b - 896) / 192; lb = (b - 896) - g * 192;
        W = g == 0 ? w5 : w6; T = g == 0 ? t5 : t6;
        K = 256; Nc = 160;
    } else {
        lb = b - 1280;
        int idx = lb * 256 + t;          // 64*256 = 16384 elems
        int n = idx >> 8, k = idx & 255;
        float v = 0.f;
        if (n < 40)
            v = 0.25f * (wr2[(size_t)k * 160 + n] + wr2[(size_t)k * 160 + 40 + n] +
                         wr2[(size_t)k * 160 + 80 + n] + wr2[(size_t)k * 160 + 120 + n]);
        teff[idx] = f2bf(v);
        if (lb == 0 && t < 40)
            b_eff[t] = 0.25f * (br2[t] + br2[40 + t] + br2[80 + t] + br2[120 + t]);
        return;
    }
    int idx = lb * 256 + t;
    int n = idx / K, k = idx - n * K;
    float v = (n < Nc) ? W[(size_t)k * Nc + n] : 0.f;
    T[idx] = f2bf(v);
}

// ---------------- CSR scan (R9-verified) ----------------

__global__ void deg_chunk_sum(const int* __restrict__ deg, int n, int* __restrict__ chunk_sums) {
    __shared__ int sm[256];
    int base = blockIdx.x * 1024;
    int s = 0;
    for (int i = threadIdx.x; i < 1024; i += 256) {
        int idx = base + i;
        if (idx < n) s += deg[idx];
    }
    sm[threadIdx.x] = s;
    __syncthreads();
    for (int off = 128; off > 0; off >>= 1) {
        if (threadIdx.x < off) sm[threadIdx.x] += sm[threadIdx.x + off];
        __syncthreads();
    }
    if (threadIdx.x == 0) chunk_sums[blockIdx.x] = sm[0];
}

__global__ void scan_chunk_sums(int* __restrict__ chunk_sums, int nchunks) {
    __shared__ int sm[256];
    int t = threadIdx.x;
    if (t < nchunks) sm[t] = chunk_sums[t];
    __syncthreads();
    if (t == 0) {
        int run = 0;
        for (int i = 0; i < nchunks; i++) { int v = sm[i]; sm[i] = run; run += v; }
    }
    __syncthreads();
    if (t < nchunks) chunk_sums[t] = sm[t];
}

__global__ void scan_write(const int* __restrict__ deg, int n,
                           const int* __restrict__ chunk_sums,
                           int* __restrict__ row_start, int Etot) {
    int base = blockIdx.x * 1024;
    int t = threadIdx.x;
    int v[4];
    int tsum = 0;
#pragma unroll
    for (int j = 0; j < 4; j++) {
        int idx = base + t * 4 + j;
        v[j] = (idx < n) ? deg[idx] : 0;
        tsum += v[j];
    }
    __shared__ int sm[256];
    sm[t] = tsum;
    __syncthreads();
    for (int off = 1; off < 256; off <<= 1) {
        int x = (t >= off) ? sm[t - off] : 0;
        __syncthreads();
        sm[t] += x;
        __syncthreads();
    }
    int excl = sm[t] - tsum + chunk_sums[blockIdx.x];
#pragma unroll
    for (int j = 0; j < 4; j++) {
        int idx = base + t * 4 + j;
        if (idx < n) row_start[idx] = excl;
        excl += v[j];
    }
    if (blockIdx.x == 0 && t == 0) row_start[n] = Etot;
}

// ---------------- single-A-stage multi-output MFMA GEMM (R14/R16 config) ----------------
// DO_SCATTER: blocks [mtiles, mtiles+eblocks) run the edge scatter (independent
// work overlapped with the layer-0 GEMM in one dispatch) and return early.

template <typename TA, int NOUT, int KTOT, int NPAD, bool SPLIT40, bool HAS_EFF, bool DO_SCATTER>
__global__ __launch_bounds__(256) void gemm_lds(
    const TA* __restrict__ A,
    const bf16_t* __restrict__ Wt0, const bf16_t* __restrict__ Wt1, const bf16_t* __restrict__ Wt2,
    const float* __restrict__ bias0, const float* __restrict__ bias1, const float* __restrict__ bias2,
    bf16_t* __restrict__ C0, bf16_t* __restrict__ C1, bf16_t* __restrict__ C2,
    const bf16_t* __restrict__ Wte, const float* __restrict__ biase, float* __restrict__ Ce,
    int M, int Nc,
    const int* __restrict__ e_dst, const int* __restrict__ e_src, int E,
    const int* __restrict__ row_start, int* __restrict__ fill,
    int* __restrict__ src_sorted, int mtiles)
{
    constexpr int LSTR = KTOT + 8;     // stage row stride
    constexpr int ESTR = 38;           // epilogue row stride
    constexpr int KC = KTOT / 32;
    __shared__ bf16_t As[64 * LSTR];
    __shared__ bf16_t Ep[4 * 64 * ESTR];

    int tid = threadIdx.x;

    if (DO_SCATTER && (int)blockIdx.x >= mtiles) {
        int e = (blockIdx.x - mtiles) * 256 + tid;
        if (e < E) {
            int d_ = e_dst[e];
            int pos = row_start[d_] + atomicAdd(&fill[d_], 1);
            src_sorted[pos] = e_src[e];
        }
        return;
    }

    int lane = tid & 63, w = tid >> 6;
    int lm = lane & 15, lq = lane >> 4;
    int m0 = blockIdx.x * 64;

    const bf16_t* Wts[3] = {Wt0, Wt1, Wt2};
    const float* biases[3] = {bias0, bias1, bias2};
    bf16_t* Cs[3] = {C0, C1, C2};

    // ---- stage A slab (64 rows x KTOT) once ----
    if (sizeof(TA) == 4) {            // KTOT == 128, f32 input
#pragma unroll
        for (int it = 0; it < 4; it++) {
            int idx = tid + it * 256;  // 1024 chunks of 8 floats
            int r = idx >> 4, c = idx & 15;
            int gm = m0 + r; if (gm >= M) gm = M - 1;
            const float* ap = (const float*)A + (size_t)gm * KTOT + c * 8;
            float4 lo = *(const float4*)ap;
            float4 hi = *(const float4*)(ap + 4);
            ushort2 p0 = pk_f2bf(lo.x, lo.y), p1 = pk_f2bf(lo.z, lo.w);
            ushort2 p2 = pk_f2bf(hi.x, hi.y), p3 = pk_f2bf(hi.z, hi.w);
            bh8 v = { (short)p0.x, (short)p0.y, (short)p1.x, (short)p1.y,
                      (short)p2.x, (short)p2.y, (short)p3.x, (short)p3.y };
            *(bh8*)(As + r * LSTR + c * 8) = v;
        }
    } else {                           // KTOT == 256, bf16 input
#pragma unroll
        for (int it = 0; it < 8; it++) {
            int idx = tid + it * 256;  // 2048 chunks of 8 bf16
            int r = idx >> 5, c = idx & 31;
            int gm = m0 + r; if (gm >= M) gm = M - 1;
            bh8 v = *(const bh8*)((const bf16_t*)A + (size_t)gm * KTOT + c * 8);
            *(bh8*)(As + r * LSTR + c * 8) = v;
        }
    }
    __syncthreads();   // the ONLY barrier

    bf16_t* ep = Ep + w * (64 * ESTR);
    constexpr int NCHUNK = (NPAD + 127) / 128;

#pragma unroll
    for (int chunk = 0; chunk < NCHUNK; chunk++) {
        int n0 = chunk * 128 + w * 32;
        if (n0 >= NPAD) continue;      // no barriers inside -> safe

        int boff[NOUT][2];
#pragma unroll
        for (int o = 0; o < NOUT; o++)
#pragma unroll
            for (int nt = 0; nt < 2; nt++)
                boff[o][nt] = (n0 + nt * 16 + lm) * KTOT + lq * 8;

        f32x4 acc[NOUT][4][2];
#pragma unroll
        for (int o = 0; o < NOUT; o++)
#pragma unroll
            for (int i = 0; i < 4; i++)
#pragma unroll
                for (int j = 0; j < 2; j++)
                    acc[o][i][j] = (f32x4){0.f, 0.f, 0.f, 0.f};

        bh8 bf_cur[NOUT][2], bf_nxt[NOUT][2];
#pragma unroll
        for (int o = 0; o < NOUT; o++)
#pragma unroll
            for (int nt = 0; nt < 2; nt++)
                bf_cur[o][nt] = *(const bh8*)(Wts[o] + boff[o][nt]);

#pragma unroll
        for (int kc = 0; kc < KC; kc++) {
            if (kc + 1 < KC) {
#pragma unroll
                for (int o = 0; o < NOUT; o++)
#pragma unroll
                    for (int nt = 0; nt < 2; nt++)
                        bf_nxt[o][nt] = *(const bh8*)(Wts[o] + boff[o][nt] + (kc + 1) * 32);
            }
            bh8 af[4];
#pragma unroll
            for (int mt = 0; mt < 4; mt++)
                af[mt] = *(const bh8*)(As + (mt * 16 + lm) * LSTR + kc * 32 + lq * 8);
#pragma unroll
            for (int o = 0; o < NOUT; o++)
#pragma unroll
                for (int mt = 0; mt < 4; mt++)
#pragma unroll
                    for (int nt = 0; nt < 2; nt++)
                        acc[o][mt][nt] = __builtin_amdgcn_mfma_f32_16x16x32_bf16(af[mt], bf_cur[o][nt], acc[o][mt][nt], 0, 0, 0);
            if (kc + 1 < KC) {
#pragma unroll
                for (int o = 0; o < NOUT; o++)
#pragma unroll
                    for (int nt = 0; nt < 2; nt++)
                        bf_cur[o][nt] = bf_nxt[o][nt];
            }
        }

        // ---- per-wave epilogue: private LDS tile -> full-line global stores ----
#pragma unroll
        for (int o = 0; o < NOUT; o++) {
#pragma unroll
            for (int nt = 0; nt < 2; nt++) {
                int gn = n0 + nt * 16 + lm;
                float bv = (gn < Nc) ? biases[o][gn] : 0.f;
#pragma unroll
                for (int mt = 0; mt < 4; mt++)
#pragma unroll
                    for (int r = 0; r < 4; r++)
                        ep[(mt * 16 + lq * 4 + r) * ESTR + nt * 16 + lm] = f2bf(acc[o][mt][nt][r] + bv);
            }
#pragma unroll
            for (int it = 0; it < 4; it++) {
                int row = it * 16 + (lane >> 2);
                int cc = (lane & 3) * 8;
                bh8 v = *(const bh8*)(ep + row * ESTR + cc);
                int gm = m0 + row;
                int cg = n0 + cc;
                if (gm < M && cg < Nc) {
                    size_t cb = SPLIT40 ? (size_t)(cg + 24 * (cg / 40)) : (size_t)cg;
                    size_t rs = SPLIT40 ? 256 : (size_t)Nc;
                    *(bh8*)(Cs[o] + (size_t)gm * rs + cb) = v;
                }
            }
        }
    }

    // ---- folded-residual pass (waves 0-1), reuses LDS A ----
    if (HAS_EFF && w < 2) {
        int beoff[2];
#pragma unroll
        for (int nt = 0; nt < 2; nt++)
            beoff[nt] = (w * 32 + nt * 16 + lm) * KTOT + lq * 8;
        f32x4 acc_e[4][2];
#pragma unroll
        for (int i = 0; i < 4; i++)
#pragma unroll
            for (int j = 0; j < 2; j++)
                acc_e[i][j] = (f32x4){0.f, 0.f, 0.f, 0.f};
#pragma unroll
        for (int kc = 0; kc < KC; kc++) {
            bh8 af[4];
#pragma unroll
            for (int mt = 0; mt < 4; mt++)
                af[mt] = *(const bh8*)(As + (mt * 16 + lm) * LSTR + kc * 32 + lq * 8);
            bh8 be[2];
#pragma unroll
            for (int nt = 0; nt < 2; nt++)
                be[nt] = *(const bh8*)(Wte + beoff[nt] + kc * 32);
#pragma unroll
            for (int mt = 0; mt < 4; mt++)
#pragma unroll
                for (int nt = 0; nt < 2; nt++)
                    acc_e[mt][nt] = __builtin_amdgcn_mfma_f32_16x16x32_bf16(af[mt], be[nt], acc_e[mt][nt], 0, 0, 0);
        }
#pragma unroll
        for (int nt = 0; nt < 2; nt++) {
            int gn = w * 32 + nt * 16 + lm;
            if (gn >= 40) continue;
            float bv = biase[gn];
#pragma unroll
            for (int mt = 0; mt < 4; mt++)
#pragma unroll
                for (int r = 0; r < 4; r++) {
                    int gm = m0 + mt * 16 + lq * 4 + r;
                    if (gm < M) Ce[(size_t)gm * 40 + gn] = acc_e[mt][nt][r] + bv;
                }
        }
    }
}

// ---------------- GATv2 aggregation: QUARTER-WAVE per node, unroll-2 (R13/R16-verified) ----------------

__device__ __forceinline__ void us8_to_f(const us8 v, float* h) {
#pragma unroll
    for (int j = 0; j < 8; j++) h[j] = bf2f(v[j]);
}

__device__ __forceinline__ float edge_logit16(const float h[16], const float hdf[16], const float at[16]) {
    float p = 0.f;
#pragma unroll
    for (int j = 0; j < 16; j++) {
        float q = h[j] + hdf[j];
        p += fmaxf(q, SLOPE * q) * at[j];
    }
    p += __shfl_xor(p, 1, 64);
    p += __shfl_xor(p, 2, 64);
    return p;
}

template <int DVALID, bool FINAL, bool RES_INPLACE>
__global__ __launch_bounds__(256) void gat_agg_quarter(
    const bf16_t* __restrict__ hs, const bf16_t* __restrict__ hd,
    const float* __restrict__ attn,
    const int* __restrict__ row_start, const int* __restrict__ src_sorted,
    bf16_t* __restrict__ P, float* __restrict__ out_final, int N)
{
    int w = threadIdx.x >> 6, lane = threadIdx.x & 63;
    int q = lane >> 4, ql = lane & 15;
    int n = blockIdx.x * 16 + w * 4 + q;
    if (n >= N) return;
    int f0 = ql * 16;         // padded feature base
    int h = ql >> 2;          // head
    int dp = (ql & 3) * 16;   // d within head (padded)

    float at[16], hdf[16];
#pragma unroll
    for (int j = 0; j < 16; j++)
        at[j] = (dp + j < DVALID) ? attn[h * DVALID + dp + j] : 0.f;
    {
        us8 a = *(const us8*)(hd + (unsigned)(n * 256 + f0));
        us8 b = *(const us8*)(hd + (unsigned)(n * 256 + f0 + 8));
        us8_to_f(a, hdf); us8_to_f(b, hdf + 8);
    }

    // per-node proxy center: logit at hs=0 (keeps exp args small; logits bounded)
    float pc;
    {
        float p = 0.f;
#pragma unroll
        for (int j = 0; j < 16; j++) {
            float qq = hdf[j];
            p += fmaxf(qq, SLOPE * qq) * at[j];
        }
        p += __shfl_xor(p, 1, 64);
        p += __shfl_xor(p, 2, 64);
        pc = p;
    }

    int s = row_start[n], e = row_start[n + 1];

    float cl0 = 0.f, cl1 = 0.f;
    float ca0[16] = {}, ca1[16] = {};

    int i = s;
    for (; i + 2 <= e; i += 2) {
        int sn0 = src_sorted[i], sn1 = src_sorted[i + 1];
        us8 r0a = *(const us8*)(hs + (unsigned)(sn0 * 256 + f0));
        us8 r0b = *(const us8*)(hs + (unsigned)(sn0 * 256 + f0 + 8));
        us8 r1a = *(const us8*)(hs + (unsigned)(sn1 * 256 + f0));
        us8 r1b = *(const us8*)(hs + (unsigned)(sn1 * 256 + f0 + 8));
        float h0[16], h1[16];
        us8_to_f(r0a, h0); us8_to_f(r0b, h0 + 8);
        us8_to_f(r1a, h1); us8_to_f(r1b, h1 + 8);
        float w0 = __expf(edge_logit16(h0, hdf, at) - pc);
        float w1 = __expf(edge_logit16(h1, hdf, at) - pc);
        cl0 += w0; cl1 += w1;
#pragma unroll
        for (int j = 0; j < 16; j++) {
            ca0[j] += w0 * h0[j];
            ca1[j] += w1 * h1[j];
        }
    }
    if (i < e) {
        int sn0 = src_sorted[i];
        us8 r0a = *(const us8*)(hs + (unsigned)(sn0 * 256 + f0));
        us8 r0b = *(const us8*)(hs + (unsigned)(sn0 * 256 + f0 + 8));
        float h0[16];
        us8_to_f(r0a, h0); us8_to_f(r0b, h0 + 8);
        float w0 = __expf(edge_logit16(h0, hdf, at) - pc);
        cl0 += w0;
#pragma unroll
        for (int j = 0; j < 16; j++) ca0[j] += w0 * h0[j];
    }

    float v[16] = {};
    if (e > s) {
        float inv = 1.f / (cl0 + cl1);
#pragma unroll
        for (int j = 0; j < 16; j++)
            v[j] = (ca0[j] + ca1[j]) * inv;
    }

    if (FINAL) {
        // head-sum: lanes ql, ql^4, ql^8, ql^12 hold the same d-range across heads
#pragma unroll
        for (int j = 0; j < 16; j++) {
            v[j] += __shfl_xor(v[j], 4, 64);
            v[j] += __shfl_xor(v[j], 8, 64);
        }
        if (h == 0) {
#pragma unroll
            for (int jj = 0; jj < 16; jj += 4) {
                if (dp + jj < DVALID) {   // DVALID % 4 == 0 -> whole float4 valid
                    float* op = out_final + (unsigned)(n * DVALID + dp + jj);
                    float4 cur = *(float4*)op;
                    cur.x += 0.25f * v[jj];
                    cur.y += 0.25f * v[jj + 1];
                    cur.z += 0.25f * v[jj + 2];
                    cur.w += 0.25f * v[jj + 3];
                    *(float4*)op = cur;
                }
            }
        }
    } else {
        unsigned oi = (unsigned)(n * 256 + f0);
        if (RES_INPLACE) {
            us8 pa = *(const us8*)(P + oi);
            us8 pb = *(const us8*)(P + oi + 8);
#pragma unroll
            for (int j = 0; j < 8; j++) {
                v[j] += bf2f(pa[j]);
                v[8 + j] += bf2f(pb[j]);
            }
        }
        us8 oa, ob;
#pragma unroll
        for (int j = 0; j < 8; j++) {
            oa[j] = f2bf(v[j]);
            ob[j] = f2bf(v[8 + j]);
        }
        *(us8*)(P + oi) = oa;
        *(us8*)(P + oi + 8) = ob;
    }
}

// ---------------- launch ----------------

extern "C" void kernel_launch(void* const* d_in, const int* in_sizes, int n_in,
                              void* d_out, int out_size, void* d_ws, size_t ws_size,
                              hipStream_t stream) {
    const float* x0    = (const float*)d_in[0];
    const int*   src   = (const int*)d_in[1];
    const int*   dst   = (const int*)d_in[2];
    const float* w_src0 = (const float*)d_in[3];  const float* b_src0 = (const float*)d_in[4];
    const float* w_dst0 = (const float*)d_in[5];  const float* b_dst0 = (const float*)d_in[6];
    const float* attn0  = (const float*)d_in[7];
    const float* w_res0 = (const float*)d_in[8];  const float* b_res0 = (const float*)d_in[9];
    const float* w_src1 = (const float*)d_in[10]; const float* b_src1 = (const float*)d_in[11];
    const float* w_dst1 = (const float*)d_in[12]; const float* b_dst1 = (const float*)d_in[13];
    const float* attn1  = (const float*)d_in[14];
    const float* w_src2 = (const float*)d_in[15]; const float* b_src2 = (const float*)d_in[16];
    const float* w_dst2 = (const float*)d_in[17]; const float* b_dst2 = (const float*)d_in[18];
    const float* attn2  = (const float*)d_in[19];
    const float* w_res2 = (const float*)d_in[20]; const float* b_res2 = (const float*)d_in[21];

    const int N = in_sizes[0] / 128;   // 50000
    const int E = in_sizes[1];         // 400000
    float* out = (float*)d_out;
    (void)n_in; (void)out_size; (void)ws_size;

    // ---- workspace (~80 MB) ----
    char* ws = (char*)d_ws;
    size_t off = 0;
    auto alloc = [&](size_t bytes) {
        void* q = ws + off;
        off = (off + bytes + 255) & ~(size_t)255;
        return q;
    };
    int* deg        = (int*)alloc((size_t)2 * N * 4);
    int* fill       = deg + N;
    int* row_start  = (int*)alloc((size_t)(N + 1) * 4);
    int* chunk_sums = (int*)alloc(256 * 4);
    int* src_sorted = (int*)alloc((size_t)E * 4);
    bf16_t* t_src0 = (bf16_t*)alloc(256 * 128 * 2);
    bf16_t* t_dst0 = (bf16_t*)alloc(256 * 128 * 2);
    bf16_t* t_res0 = (bf16_t*)alloc(256 * 128 * 2);
    bf16_t* t_src1 = (bf16_t*)alloc(256 * 256 * 2);
    bf16_t* t_dst1 = (bf16_t*)alloc(256 * 256 * 2);
    bf16_t* t_src2 = (bf16_t*)alloc(192 * 256 * 2);
    bf16_t* t_dst2 = (bf16_t*)alloc(192 * 256 * 2);
    bf16_t* t_eff  = (bf16_t*)alloc(64 * 256 * 2);
    float*  b_eff  = (float*)alloc(64 * 4);
    const size_t elems = (size_t)N * 256;
    bf16_t* P  = (bf16_t*)alloc(elems * 2);
    bf16_t* HS = (bf16_t*)alloc(elems * 2);
    bf16_t* HD = (bf16_t*)alloc(elems * 2);

    // ---- CSR build + weight conversion ----
    hipMemsetAsync(deg, 0, (size_t)2 * N * 4, stream);
    int eblocks = (E + 255) / 256;     // 1563
    int nchunks = (N + 1023) / 1024;
    hipLaunchKernelGGL(hist_and_convert, dim3(eblocks + 1344), dim3(256), 0, stream,
                       dst, E, eblocks, deg,
                       w_src0, w_dst0, w_res0, w_src1, w_dst1, w_src2, w_dst2, w_res2, b_res2,
                       t_src0, t_dst0, t_res0, t_src1, t_dst1, t_src2, t_dst2, t_eff, b_eff);
    hipLaunchKernelGGL(deg_chunk_sum, dim3(nchunks), dim3(256), 0, stream, deg, N, chunk_sums);
    hipLaunchKernelGGL(scan_chunk_sums, dim3(1), dim3(256), 0, stream, chunk_sums, nchunks);
    hipLaunchKernelGGL(scan_write, dim3(nchunks), dim3(256), 0, stream, deg, N, chunk_sums, row_start, E);

    dim3 blk(256);
    int mtiles = (N + 63) / 64;        // 782
    int ab = (N + 15) / 16;            // 3125 (quarter-wave-per-node agg)

    // ---- Layer 0: fused hs|hd|res GEMM from x0, OVERLAPPED with edge scatter ----
    hipLaunchKernelGGL((gemm_lds<float, 3, 128, 256, false, false, true>),
                       dim3(mtiles + eblocks), blk, 0, stream,
                       x0, t_src0, t_dst0, t_res0, b_src0, b_dst0, b_res0,
                       HS, HD, P,
                       (const bf16_t*)nullptr, (const float*)nullptr, (float*)nullptr,
                       N, 256,
                       dst, src, E, row_start, fill, src_sorted, mtiles);
    hipLaunchKernelGGL((gat_agg_quarter<64, false, true>), dim3(ab), blk, 0, stream,
                       HS, HD, attn0, row_start, src_sorted, P, (float*)nullptr, N);

    // ---- Layer 1: fused hs|hd from P; identity residual in-place ----
    hipLaunchKernelGGL((gemm_lds<bf16_t, 2, 256, 256, false, false, false>), dim3(mtiles), blk, 0, stream,
                       P, t_src1, t_dst1, (const bf16_t*)nullptr, b_src1, b_dst1, (const float*)nullptr,
                       HS, HD, (bf16_t*)nullptr,
                       (const bf16_t*)nullptr, (const float*)nullptr, (float*)nullptr,
                       N, 256,
                       (const int*)nullptr, (const int*)nullptr, 0,
                       (const int*)nullptr, (int*)nullptr, (int*)nullptr, 0);
    hipLaunchKernelGGL((gat_agg_quarter<64, false, true>), dim3(ab), blk, 0, stream,
                       HS, HD, attn1, row_start, src_sorted, P, (float*)nullptr, N);

    // ---- Layer 2: fused hs|hd (SPLIT40) + eff residual (f32 -> out); FINAL agg accumulates ----
    hipLaunchKernelGGL((gemm_lds<bf16_t, 2, 256, 192, true, true, false>), dim3(mtiles), blk, 0, stream,
                       P, t_src2, t_dst2, (const bf16_t*)nullptr, b_src2, b_dst2, (const float*)nullptr,
                       HS, HD, (bf16_t*)nullptr,
                       t_eff, b_eff, out,
                       N, 160,
                       (const int*)nullptr, (const int*)nullptr, 0,
                       (const int*)nullptr, (int*)nullptr, (int*)nullptr, 0);
    hipLaunchKernelGGL((gat_agg_quarter<40, true, false>), dim3(ab), blk, 0, stream,
                       HS, HD, attn2, row_start, src_sorted, (bf16_t*)nullptr, out, N);
}

// Round 18
// 410.901 us; speedup vs baseline: 1.1410x; 1.0209x over previous
//
#include <hip/hip_runtime.h>
#include <hip/hip_bf16.h>
#include <math.h>

// N=50000, E=400000, F_IN=128, HID=64, OUT=40, H=4
#define SLOPE 0.2f

typedef unsigned short bf16_t;
typedef short bh8 __attribute__((ext_vector_type(8)));
typedef unsigned short us8 __attribute__((ext_vector_type(8)));
typedef float f32x4 __attribute__((ext_vector_type(4)));

__device__ __forceinline__ float bf2f(bf16_t x) {
    return __uint_as_float((unsigned)x << 16);
}
__device__ __forceinline__ bf16_t f2bf(float v) {
    unsigned u = __float_as_uint(v);
    return (bf16_t)((u + 0x7FFFu + ((u >> 16) & 1u)) >> 16);  // RNE
}
__device__ __forceinline__ ushort2 pk_f2bf(float a, float b) {
    __hip_bfloat162 h2 = __float22bfloat162_rn(float2{a, b});  // v_cvt_pk_bf16_f32
    union { __hip_bfloat162 h; ushort2 u; } u;
    u.h = h2;
    return u.u;
}

// ---------------- fused histogram + weight conversion (R15/R16-verified) ----------------

__global__ void hist_and_convert(
    const int* __restrict__ dst, int E, int eblocks, int* __restrict__ deg,
    const float* __restrict__ w0, const float* __restrict__ w1, const float* __restrict__ w2,
    const float* __restrict__ w3, const float* __restrict__ w4,
    const float* __restrict__ w5, const float* __restrict__ w6,
    const float* __restrict__ wr2, const float* __restrict__ br2,
    bf16_t* __restrict__ t0, bf16_t* __restrict__ t1, bf16_t* __restrict__ t2,
    bf16_t* __restrict__ t3, bf16_t* __restrict__ t4,
    bf16_t* __restrict__ t5, bf16_t* __restrict__ t6,
    bf16_t* __restrict__ teff, float* __restrict__ b_eff)
{
    int t = threadIdx.x;
    if ((int)blockIdx.x < eblocks) {
        int e = blockIdx.x * 256 + t;
        if (e < E) atomicAdd(&deg[dst[e]], 1);
        return;
    }
    int b = blockIdx.x - eblocks;
    const float* W; bf16_t* T; int K, Nc, lb;
    if (b < 384) {
        int g = b / 128; lb = b - g * 128;
        W = g == 0 ? w0 : (g == 1 ? w1 : w2);
        T = g == 0 ? t0 : (g == 1 ? t1 : t2);
        K = 128; Nc = 256;
    } else if (b < 896) {
        int g = (b - 384) / 256; lb = (b - 384) - g * 256;
        W = g == 0 ? w3 : w4; T = g == 0 ? t3 : t4;
        K = 256; Nc = 256;
    } else if (b < 1280) {
        int g = (b - 896) / 192; lb = (b - 896) - g * 192;
        W = g == 0 ? w5 : w6; T = g == 0 ? t5 : t6;
        K = 256; Nc = 160;
    } else {
        lb = b - 1280;
        int idx = lb * 256 + t;          // 64*256 = 16384 elems
        int n = idx >> 8, k = idx & 255;
        float v = 0.f;
        if (n < 40)
            v = 0.25f * (wr2[(size_t)k * 160 + n] + wr2[(size_t)k * 160 + 40 + n] +
                         wr2[(size_t)k * 160 + 80 + n] + wr2[(size_t)k * 160 + 120 + n]);
        teff[idx] = f2bf(v);
        if (lb == 0 && t < 40)
            b_eff[t] = 0.25f * (br2[t] + br2[40 + t] + br2[80 + t] + br2[120 + t]);
        return;
    }
    int idx = lb * 256 + t;
    int n = idx / K, k = idx - n * K;
    float v = (n < Nc) ? W[(size_t)k * Nc + n] : 0.f;
    T[idx] = f2bf(v);
}

// ---------------- CSR scan (2-kernel: chunk sums, then write with in-block prefix) ----------------

__global__ void deg_chunk_sum(const int* __restrict__ deg, int n, int* __restrict__ chunk_sums) {
    __shared__ int sm[256];
    int base = blockIdx.x * 1024;
    int s = 0;
    for (int i = threadIdx.x; i < 1024; i += 256) {
        int idx = base + i;
        if (idx < n) s += deg[idx];
    }
    sm[threadIdx.x] = s;
    __syncthreads();
    for (int off = 128; off > 0; off >>= 1) {
        if (threadIdx.x < off) sm[threadIdx.x] += sm[threadIdx.x + off];
        __syncthreads();
    }
    if (threadIdx.x == 0) chunk_sums[blockIdx.x] = sm[0];
}

// each block computes its own chunk-prefix from chunk_sums (nchunks <= 64)
__global__ void scan_write(const int* __restrict__ deg, int n,
                           const int* __restrict__ chunk_sums,
                           int* __restrict__ row_start, int Etot) {
    __shared__ int sm[256];
    __shared__ int s_pref;
    int base = blockIdx.x * 1024;
    int t = threadIdx.x;

    // wave 0: sum chunk_sums[0..blockIdx.x) via wave-reduce
    if (t < 64) {
        int v = (t < (int)blockIdx.x) ? chunk_sums[t] : 0;
#pragma unroll
        for (int off = 32; off > 0; off >>= 1)
            v += __shfl_down(v, off, 64);
        if (t == 0) s_pref = v;
    }

    int vv[4];
    int tsum = 0;
#pragma unroll
    for (int j = 0; j < 4; j++) {
        int idx = base + t * 4 + j;
        vv[j] = (idx < n) ? deg[idx] : 0;
        tsum += vv[j];
    }
    sm[t] = tsum;
    __syncthreads();
    for (int off = 1; off < 256; off <<= 1) {
        int x = (t >= off) ? sm[t - off] : 0;
        __syncthreads();
        sm[t] += x;
        __syncthreads();
    }
    int excl = sm[t] - tsum + s_pref;
#pragma unroll
    for (int j = 0; j < 4; j++) {
        int idx = base + t * 4 + j;
        if (idx < n) row_start[idx] = excl;
        excl += vv[j];
    }
    if (blockIdx.x == 0 && t == 0) row_start[n] = Etot;
}

// ---------------- single-A-stage multi-output MFMA GEMM (R14/R17 config) ----------------
// DO_SCATTER: blocks [mtiles, mtiles+eblocks) run the edge scatter (independent
// work overlapped with the layer-0 GEMM in one dispatch) and return early.

template <typename TA, int NOUT, int KTOT, int NPAD, bool SPLIT40, bool HAS_EFF, bool DO_SCATTER>
__global__ __launch_bounds__(256) void gemm_lds(
    const TA* __restrict__ A,
    const bf16_t* __restrict__ Wt0, const bf16_t* __restrict__ Wt1, const bf16_t* __restrict__ Wt2,
    const float* __restrict__ bias0, const float* __restrict__ bias1, const float* __restrict__ bias2,
    bf16_t* __restrict__ C0, bf16_t* __restrict__ C1, bf16_t* __restrict__ C2,
    const bf16_t* __restrict__ Wte, const float* __restrict__ biase, float* __restrict__ Ce,
    int M, int Nc,
    const int* __restrict__ e_dst, const int* __restrict__ e_src, int E,
    const int* __restrict__ row_start, int* __restrict__ fill,
    int* __restrict__ src_sorted, int mtiles)
{
    constexpr int LSTR = KTOT + 8;     // stage row stride
    constexpr int ESTR = 38;           // epilogue row stride
    constexpr int KC = KTOT / 32;
    __shared__ bf16_t As[64 * LSTR];
    __shared__ bf16_t Ep[4 * 64 * ESTR];

    int tid = threadIdx.x;

    if (DO_SCATTER && (int)blockIdx.x >= mtiles) {
        int e = (blockIdx.x - mtiles) * 256 + tid;
        if (e < E) {
            int d_ = e_dst[e];
            int pos = row_start[d_] + atomicAdd(&fill[d_], 1);
            src_sorted[pos] = e_src[e];
        }
        return;
    }

    int lane = tid & 63, w = tid >> 6;
    int lm = lane & 15, lq = lane >> 4;
    int m0 = blockIdx.x * 64;

    const bf16_t* Wts[3] = {Wt0, Wt1, Wt2};
    const float* biases[3] = {bias0, bias1, bias2};
    bf16_t* Cs[3] = {C0, C1, C2};

    // ---- stage A slab (64 rows x KTOT) once ----
    if (sizeof(TA) == 4) {            // KTOT == 128, f32 input
#pragma unroll
        for (int it = 0; it < 4; it++) {
            int idx = tid + it * 256;  // 1024 chunks of 8 floats
            int r = idx >> 4, c = idx & 15;
            int gm = m0 + r; if (gm >= M) gm = M - 1;
            const float* ap = (const float*)A + (size_t)gm * KTOT + c * 8;
            float4 lo = *(const float4*)ap;
            float4 hi = *(const float4*)(ap + 4);
            ushort2 p0 = pk_f2bf(lo.x, lo.y), p1 = pk_f2bf(lo.z, lo.w);
            ushort2 p2 = pk_f2bf(hi.x, hi.y), p3 = pk_f2bf(hi.z, hi.w);
            bh8 v = { (short)p0.x, (short)p0.y, (short)p1.x, (short)p1.y,
                      (short)p2.x, (short)p2.y, (short)p3.x, (short)p3.y };
            *(bh8*)(As + r * LSTR + c * 8) = v;
        }
    } else {                           // KTOT == 256, bf16 input
#pragma unroll
        for (int it = 0; it < 8; it++) {
            int idx = tid + it * 256;  // 2048 chunks of 8 bf16
            int r = idx >> 5, c = idx & 31;
            int gm = m0 + r; if (gm >= M) gm = M - 1;
            bh8 v = *(const bh8*)((const bf16_t*)A + (size_t)gm * KTOT + c * 8);
            *(bh8*)(As + r * LSTR + c * 8) = v;
        }
    }
    __syncthreads();   // the ONLY barrier

    bf16_t* ep = Ep + w * (64 * ESTR);
    constexpr int NCHUNK = (NPAD + 127) / 128;

#pragma unroll
    for (int chunk = 0; chunk < NCHUNK; chunk++) {
        int n0 = chunk * 128 + w * 32;
        if (n0 >= NPAD) continue;      // no barriers inside -> safe

        int boff[NOUT][2];
#pragma unroll
        for (int o = 0; o < NOUT; o++)
#pragma unroll
            for (int nt = 0; nt < 2; nt++)
                boff[o][nt] = (n0 + nt * 16 + lm) * KTOT + lq * 8;

        f32x4 acc[NOUT][4][2];
#pragma unroll
        for (int o = 0; o < NOUT; o++)
#pragma unroll
            for (int i = 0; i < 4; i++)
#pragma unroll
                for (int j = 0; j < 2; j++)
                    acc[o][i][j] = (f32x4){0.f, 0.f, 0.f, 0.f};

        bh8 bf_cur[NOUT][2], bf_nxt[NOUT][2];
#pragma unroll
        for (int o = 0; o < NOUT; o++)
#pragma unroll
            for (int nt = 0; nt < 2; nt++)
                bf_cur[o][nt] = *(const bh8*)(Wts[o] + boff[o][nt]);

#pragma unroll
        for (int kc = 0; kc < KC; kc++) {
            if (kc + 1 < KC) {
#pragma unroll
                for (int o = 0; o < NOUT; o++)
#pragma unroll
                    for (int nt = 0; nt < 2; nt++)
                        bf_nxt[o][nt] = *(const bh8*)(Wts[o] + boff[o][nt] + (kc + 1) * 32);
            }
            bh8 af[4];
#pragma unroll
            for (int mt = 0; mt < 4; mt++)
                af[mt] = *(const bh8*)(As + (mt * 16 + lm) * LSTR + kc * 32 + lq * 8);
#pragma unroll
            for (int o = 0; o < NOUT; o++)
#pragma unroll
                for (int mt = 0; mt < 4; mt++)
#pragma unroll
                    for (int nt = 0; nt < 2; nt++)
                        acc[o][mt][nt] = __builtin_amdgcn_mfma_f32_16x16x32_bf16(af[mt], bf_cur[o][nt], acc[o][mt][nt], 0, 0, 0);
            if (kc + 1 < KC) {
#pragma unroll
                for (int o = 0; o < NOUT; o++)
#pragma unroll
                    for (int nt = 0; nt < 2; nt++)
                        bf_cur[o][nt] = bf_nxt[o][nt];
            }
        }

        // ---- per-wave epilogue: private LDS tile -> full-line global stores ----
#pragma unroll
        for (int o = 0; o < NOUT; o++) {
#pragma unroll
            for (int nt = 0; nt < 2; nt++) {
                int gn = n0 + nt * 16 + lm;
                float bv = (gn < Nc) ? biases[o][gn] : 0.f;
#pragma unroll
                for (int mt = 0; mt < 4; mt++)
#pragma unroll
                    for (int r = 0; r < 4; r++)
                        ep[(mt * 16 + lq * 4 + r) * ESTR + nt * 16 + lm] = f2bf(acc[o][mt][nt][r] + bv);
            }
#pragma unroll
            for (int it = 0; it < 4; it++) {
                int row = it * 16 + (lane >> 2);
                int cc = (lane & 3) * 8;
                bh8 v = *(const bh8*)(ep + row * ESTR + cc);
                int gm = m0 + row;
                int cg = n0 + cc;
                if (gm < M && cg < Nc) {
                    size_t cb = SPLIT40 ? (size_t)(cg + 24 * (cg / 40)) : (size_t)cg;
                    size_t rs = SPLIT40 ? 256 : (size_t)Nc;
                    *(bh8*)(Cs[o] + (size_t)gm * rs + cb) = v;
                }
            }
        }
    }

    // ---- folded-residual pass (waves 0-1), reuses LDS A ----
    if (HAS_EFF && w < 2) {
        int beoff[2];
#pragma unroll
        for (int nt = 0; nt < 2; nt++)
            beoff[nt] = (w * 32 + nt * 16 + lm) * KTOT + lq * 8;
        f32x4 acc_e[4][2];
#pragma unroll
        for (int i = 0; i < 4; i++)
#pragma unroll
            for (int j = 0; j < 2; j++)
                acc_e[i][j] = (f32x4){0.f, 0.f, 0.f, 0.f};
#pragma unroll
        for (int kc = 0; kc < KC; kc++) {
            bh8 af[4];
#pragma unroll
            for (int mt = 0; mt < 4; mt++)
                af[mt] = *(const bh8*)(As + (mt * 16 + lm) * LSTR + kc * 32 + lq * 8);
            bh8 be[2];
#pragma unroll
            for (int nt = 0; nt < 2; nt++)
                be[nt] = *(const bh8*)(Wte + beoff[nt] + kc * 32);
#pragma unroll
            for (int mt = 0; mt < 4; mt++)
#pragma unroll
                for (int nt = 0; nt < 2; nt++)
                    acc_e[mt][nt] = __builtin_amdgcn_mfma_f32_16x16x32_bf16(af[mt], be[nt], acc_e[mt][nt], 0, 0, 0);
        }
#pragma unroll
        for (int nt = 0; nt < 2; nt++) {
            int gn = w * 32 + nt * 16 + lm;
            if (gn >= 40) continue;
            float bv = biase[gn];
#pragma unroll
            for (int mt = 0; mt < 4; mt++)
#pragma unroll
                for (int r = 0; r < 4; r++) {
                    int gm = m0 + mt * 16 + lq * 4 + r;
                    if (gm < M) Ce[(size_t)gm * 40 + gn] = acc_e[mt][nt][r] + bv;
                }
        }
    }
}

// ---------------- GATv2 aggregation: QUARTER-WAVE per node, unroll-2 (R13/R16-verified) ----------------

__device__ __forceinline__ void us8_to_f(const us8 v, float* h) {
#pragma unroll
    for (int j = 0; j < 8; j++) h[j] = bf2f(v[j]);
}

__device__ __forceinline__ float edge_logit16(const float h[16], const float hdf[16], const float at[16]) {
    float p = 0.f;
#pragma unroll
    for (int j = 0; j < 16; j++) {
        float q = h[j] + hdf[j];
        p += fmaxf(q, SLOPE * q) * at[j];
    }
    p += __shfl_xor(p, 1, 64);
    p += __shfl_xor(p, 2, 64);
    return p;
}

template <int DVALID, bool FINAL, bool RES_INPLACE>
__global__ __launch_bounds__(256) void gat_agg_quarter(
    const bf16_t* __restrict__ hs, const bf16_t* __restrict__ hd,
    const float* __restrict__ attn,
    const int* __restrict__ row_start, const int* __restrict__ src_sorted,
    bf16_t* __restrict__ P, float* __restrict__ out_final, int N)
{
    int w = threadIdx.x >> 6, lane = threadIdx.x & 63;
    int q = lane >> 4, ql = lane & 15;
    int n = blockIdx.x * 16 + w * 4 + q;
    if (n >= N) return;
    int f0 = ql * 16;         // padded feature base
    int h = ql >> 2;          // head
    int dp = (ql & 3) * 16;   // d within head (padded)

    float at[16], hdf[16];
#pragma unroll
    for (int j = 0; j < 16; j++)
        at[j] = (dp + j < DVALID) ? attn[h * DVALID + dp + j] : 0.f;
    {
        us8 a = *(const us8*)(hd + (unsigned)(n * 256 + f0));
        us8 b = *(const us8*)(hd + (unsigned)(n * 256 + f0 + 8));
        us8_to_f(a, hdf); us8_to_f(b, hdf + 8);
    }

    // per-node proxy center: logit at hs=0 (keeps exp args small; logits bounded)
    float pc;
    {
        float p = 0.f;
#pragma unroll
        for (int j = 0; j < 16; j++) {
            float qq = hdf[j];
            p += fmaxf(qq, SLOPE * qq) * at[j];
        }
        p += __shfl_xor(p, 1, 64);
        p += __shfl_xor(p, 2, 64);
        pc = p;
    }

    int s = row_start[n], e = row_start[n + 1];

    float cl0 = 0.f, cl1 = 0.f;
    float ca0[16] = {}, ca1[16] = {};

    int i = s;
    for (; i + 2 <= e; i += 2) {
        int sn0 = src_sorted[i], sn1 = src_sorted[i + 1];
        us8 r0a = *(const us8*)(hs + (unsigned)(sn0 * 256 + f0));
        us8 r0b = *(const us8*)(hs + (unsigned)(sn0 * 256 + f0 + 8));
        us8 r1a = *(const us8*)(hs + (unsigned)(sn1 * 256 + f0));
        us8 r1b = *(const us8*)(hs + (unsigned)(sn1 * 256 + f0 + 8));
        float h0[16], h1[16];
        us8_to_f(r0a, h0); us8_to_f(r0b, h0 + 8);
        us8_to_f(r1a, h1); us8_to_f(r1b, h1 + 8);
        float w0 = __expf(edge_logit16(h0, hdf, at) - pc);
        float w1 = __expf(edge_logit16(h1, hdf, at) - pc);
        cl0 += w0; cl1 += w1;
#pragma unroll
        for (int j = 0; j < 16; j++) {
            ca0[j] += w0 * h0[j];
            ca1[j] += w1 * h1[j];
        }
    }
    if (i < e) {
        int sn0 = src_sorted[i];
        us8 r0a = *(const us8*)(hs + (unsigned)(sn0 * 256 + f0));
        us8 r0b = *(const us8*)(hs + (unsigned)(sn0 * 256 + f0 + 8));
        float h0[16];
        us8_to_f(r0a, h0); us8_to_f(r0b, h0 + 8);
        float w0 = __expf(edge_logit16(h0, hdf, at) - pc);
        cl0 += w0;
#pragma unroll
        for (int j = 0; j < 16; j++) ca0[j] += w0 * h0[j];
    }

    float v[16] = {};
    if (e > s) {
        float inv = 1.f / (cl0 + cl1);
#pragma unroll
        for (int j = 0; j < 16; j++)
            v[j] = (ca0[j] + ca1[j]) * inv;
    }

    if (FINAL) {
        // head-sum: lanes ql, ql^4, ql^8, ql^12 hold the same d-range across heads
#pragma unroll
        for (int j = 0; j < 16; j++) {
            v[j] += __shfl_xor(v[j], 4, 64);
            v[j] += __shfl_xor(v[j], 8, 64);
        }
        if (h == 0) {
#pragma unroll
            for (int jj = 0; jj < 16; jj += 4) {
                if (dp + jj < DVALID) {   // DVALID % 4 == 0 -> whole float4 valid
                    float* op = out_final + (unsigned)(n * DVALID + dp + jj);
                    float4 cur = *(float4*)op;
                    cur.x += 0.25f * v[jj];
                    cur.y += 0.25f * v[jj + 1];
                    cur.z += 0.25f * v[jj + 2];
                    cur.w += 0.25f * v[jj + 3];
                    *(float4*)op = cur;
                }
            }
        }
    } else {
        unsigned oi = (unsigned)(n * 256 + f0);
        if (RES_INPLACE) {
            us8 pa = *(const us8*)(P + oi);
            us8 pb = *(const us8*)(P + oi + 8);
#pragma unroll
            for (int j = 0; j < 8; j++) {
                v[j] += bf2f(pa[j]);
                v[8 + j] += bf2f(pb[j]);
            }
        }
        us8 oa, ob;
#pragma unroll
        for (int j = 0; j < 8; j++) {
            oa[j] = f2bf(v[j]);
            ob[j] = f2bf(v[8 + j]);
        }
        *(us8*)(P + oi) = oa;
        *(us8*)(P + oi + 8) = ob;
    }
}

// ---------------- launch ----------------

extern "C" void kernel_launch(void* const* d_in, const int* in_sizes, int n_in,
                              void* d_out, int out_size, void* d_ws, size_t ws_size,
                              hipStream_t stream) {
    const float* x0    = (const float*)d_in[0];
    const int*   src   = (const int*)d_in[1];
    const int*   dst   = (const int*)d_in[2];
    const float* w_src0 = (const float*)d_in[3];  const float* b_src0 = (const float*)d_in[4];
    const float* w_dst0 = (const float*)d_in[5];  const float* b_dst0 = (const float*)d_in[6];
    const float* attn0  = (const float*)d_in[7];
    const float* w_res0 = (const float*)d_in[8];  const float* b_res0 = (const float*)d_in[9];
    const float* w_src1 = (const float*)d_in[10]; const float* b_src1 = (const float*)d_in[11];
    const float* w_dst1 = (const float*)d_in[12]; const float* b_dst1 = (const float*)d_in[13];
    const float* attn1  = (const float*)d_in[14];
    const float* w_src2 = (const float*)d_in[15]; const float* b_src2 = (const float*)d_in[16];
    const float* w_dst2 = (const float*)d_in[17]; const float* b_dst2 = (const float*)d_in[18];
    const float* attn2  = (const float*)d_in[19];
    const float* w_res2 = (const float*)d_in[20]; const float* b_res2 = (const float*)d_in[21];

    const int N = in_sizes[0] / 128;   // 50000
    const int E = in_sizes[1];         // 400000
    float* out = (float*)d_out;
    (void)n_in; (void)out_size; (void)ws_size;

    // ---- workspace (~80 MB) ----
    char* ws = (char*)d_ws;
    size_t off = 0;
    auto alloc = [&](size_t bytes) {
        void* q = ws + off;
        off = (off + bytes + 255) & ~(size_t)255;
        return q;
    };
    int* deg        = (int*)alloc((size_t)2 * N * 4);
    int* fill       = deg + N;
    int* row_start  = (int*)alloc((size_t)(N + 1) * 4);
    int* chunk_sums = (int*)alloc(256 * 4);
    int* src_sorted = (int*)alloc((size_t)E * 4);
    bf16_t* t_src0 = (bf16_t*)alloc(256 * 128 * 2);
    bf16_t* t_dst0 = (bf16_t*)alloc(256 * 128 * 2);
    bf16_t* t_res0 = (bf16_t*)alloc(256 * 128 * 2);
    bf16_t* t_src1 = (bf16_t*)alloc(256 * 256 * 2);
    bf16_t* t_dst1 = (bf16_t*)alloc(256 * 256 * 2);
    bf16_t* t_src2 = (bf16_t*)alloc(192 * 256 * 2);
    bf16_t* t_dst2 = (bf16_t*)alloc(192 * 256 * 2);
    bf16_t* t_eff  = (bf16_t*)alloc(64 * 256 * 2);
    float*  b_eff  = (float*)alloc(64 * 4);
    const size_t elems = (size_t)N * 256;
    bf16_t* P  = (bf16_t*)alloc(elems * 2);
    bf16_t* HS = (bf16_t*)alloc(elems * 2);
    bf16_t* HD = (bf16_t*)alloc(elems * 2);

    // ---- CSR build + weight conversion ----
    hipMemsetAsync(deg, 0, (size_t)2 * N * 4, stream);
    int eblocks = (E + 255) / 256;     // 1563
    int nchunks = (N + 1023) / 1024;   // 49 (<= 64 required by scan_write)
    hipLaunchKernelGGL(hist_and_convert, dim3(eblocks + 1344), dim3(256), 0, stream,
                       dst, E, eblocks, deg,
                       w_src0, w_dst0, w_res0, w_src1, w_dst1, w_src2, w_dst2, w_res2, b_res2,
                       t_src0, t_dst0, t_res0, t_src1, t_dst1, t_src2, t_dst2, t_eff, b_eff);
    hipLaunchKernelGGL(deg_chunk_sum, dim3(nchunks), dim3(256), 0, stream, deg, N, chunk_sums);
    hipLaunchKernelGGL(scan_write, dim3(nchunks), dim3(256), 0, stream, deg, N, chunk_sums, row_start, E);

    dim3 blk(256);
    int mtiles = (N + 63) / 64;        // 782
    int ab = (N + 15) / 16;            // 3125 (quarter-wave-per-node agg)

    // ---- Layer 0: fused hs|hd|res GEMM from x0, OVERLAPPED with edge scatter ----
    hipLaunchKernelGGL((gemm_lds<float, 3, 128, 256, false, false, true>),
                       dim3(mtiles + eblocks), blk, 0, stream,
                       x0, t_src0, t_dst0, t_res0, b_src0, b_dst0, b_res0,
                       HS, HD, P,
                       (const bf16_t*)nullptr, (const float*)nullptr, (float*)nullptr,
                       N, 256,
                       dst, src, E, row_start, fill, src_sorted, mtiles);
    hipLaunchKernelGGL((gat_agg_quarter<64, false, true>), dim3(ab), blk, 0, stream,
                       HS, HD, attn0, row_start, src_sorted, P, (float*)nullptr, N);

    // ---- Layer 1: fused hs|hd from P; identity residual in-place ----
    hipLaunchKernelGGL((gemm_lds<bf16_t, 2, 256, 256, false, false, false>), dim3(mtiles), blk, 0, stream,
                       P, t_src1, t_dst1, (const bf16_t*)nullptr, b_src1, b_dst1, (const float*)nullptr,
                       HS, HD, (bf16_t*)nullptr,
                       (const bf16_t*)nullptr, (const float*)nullptr, (float*)nullptr,
                       N, 256,
                       (const int*)nullptr, (const int*)nullptr, 0,
                       (const int*)nullptr, (int*)nullptr, (int*)nullptr, 0);
    hipLaunchKernelGGL((gat_agg_quarter<64, false, true>), dim3(ab), blk, 0, stream,
                       HS, HD, attn1, row_start, src_sorted, P, (float*)nullptr, N);

    // ---- Layer 2: fused hs|hd (SPLIT40) + eff residual (f32 -> out); FINAL agg accumulates ----
    hipLaunchKernelGGL((gemm_lds<bf16_t, 2, 256, 192, true, true, false>), dim3(mtiles), blk, 0, stream,
                       P, t_src2, t_dst2, (const bf16_t*)nullptr, b_src2, b_dst2, (const float*)nullptr,
                       HS, HD, (bf16_t*)nullptr,
                       t_eff, b_eff, out,
                       N, 160,
                       (const int*)nullptr, (const int*)nullptr, 0,
                       (const int*)nullptr, (int*)nullptr, (int*)nullptr, 0);
    hipLaunchKernelGGL((gat_agg_quarter<40, true, false>), dim3(ab), blk, 0, stream,
                       HS, HD, attn2, row_start, src_sorted, (bf16_t*)nullptr, out, N);
}